// Round 5
// baseline (1142.201 us; speedup 1.0000x reference)
//
#include <hip/hip_runtime.h>
#include <stdint.h>

typedef unsigned short u16;
typedef unsigned int u32;
typedef __bf16 bf16x8 __attribute__((ext_vector_type(8)));
typedef float f32x4 __attribute__((ext_vector_type(4)));

#define NGRAPH 128

__device__ __forceinline__ float b2f(u16 u) {
    union { u32 i; float f; } c; c.i = ((u32)u) << 16; return c.f;
}
__device__ __forceinline__ u16 f2b(float f) {
    union { float f; u32 i; } c; c.f = f;
    u32 r = c.i + 0x7fffu + ((c.i >> 16) & 1u);
    return (u16)(r >> 16);
}

// ---- sentinel ----
__global__ void k_sentinel(u16* __restrict__ out, int n, u16 pat) {
    int i = blockIdx.x * 256 + threadIdx.x;
    if (i < n) out[i] = pat;
}

// ---- dtype detection ----
__global__ void k_detect(const u16* __restrict__ x, int* __restrict__ flag) {
    __shared__ int cnt;
    if (threadIdx.x == 0) cnt = 0;
    __syncthreads();
    int weird = 0;
    for (int i = threadIdx.x; i < 4096; i += 256) {
        u16 u = x[2 * i];
        int e = (u >> 7) & 0xff;
        if (e != 0 && (e < 100 || e > 140)) weird++;
    }
    atomicAdd(&cnt, weird);
    __syncthreads();
    if (threadIdx.x == 0) *flag = (cnt > 1024) ? 1 : 0;   // 1 = fp32 inputs
}

// ---- convert ----
__global__ __launch_bounds__(256) void k_cvt(const void* __restrict__ src, u16* __restrict__ dst,
                                             int n, const int* __restrict__ flag) {
    int f = *flag;
    int i = blockIdx.x * 256 + threadIdx.x;
    if (i < n) dst[i] = f ? f2b(((const float*)src)[i]) : ((const u16*)src)[i];
}

__global__ __launch_bounds__(256) void k_cvt_small(
    const void* p0, const void* p1, const void* p2, const void* p3, const void* p4,
    const void* p5, const void* p6, const void* p7, const void* p8, const void* p9,
    const void* p10, const void* p11, const void* p12, const void* p13, const void* p14,
    const void* p15, const void* p16, const void* p17,
    u16* __restrict__ dst, const int* __restrict__ flag) {
    const void* ps[18] = {p0,p1,p2,p3,p4,p5,p6,p7,p8,p9,p10,p11,p12,p13,p14,p15,p16,p17};
    int f = *flag;
    int vec = blockIdx.x;
    int j = threadIdx.x;
    const void* s = ps[vec];
    dst[vec * 256 + j] = f ? f2b(((const float*)s)[j]) : ((const u16*)s)[j];
}

// ---- zero init ----
__global__ void k_zero(int* __restrict__ deg, float* __restrict__ pool, int nd, int np) {
    int i = blockIdx.x * blockDim.x + threadIdx.x;
    if (i < nd) deg[i] = 0;
    if (i < np) pool[i] = 0.0f;
}

// ---- transpose 256x256 ----
__global__ void k_transpose(const u16* __restrict__ w, u16* __restrict__ wt) {
    int idx = blockIdx.x * 256 + threadIdx.x;
    int n = idx >> 8, k = idx & 255;
    wt[n * 256 + k] = w[k * 256 + n];
}

__global__ void k_root(const int* __restrict__ batch, int* __restrict__ root, int N, int B) {
    int b = threadIdx.x;
    if (b > B) return;
    int lo = 0, hi = N;
    while (lo < hi) { int mid = (lo + hi) >> 1; if (batch[mid] < b) lo = mid + 1; else hi = mid; }
    root[b] = lo;
}

__global__ __launch_bounds__(256) void k_hist(const int* __restrict__ ei, int* __restrict__ deg, int E) {
    int e = blockIdx.x * 256 + threadIdx.x;
    if (e < E) atomicAdd(&deg[ei[E + e]], 1);
}

__global__ __launch_bounds__(256) void k_scan1(const int* __restrict__ in, int* __restrict__ out,
                                               int* __restrict__ bsums, int total) {
    __shared__ int lds[256];
    int tid = threadIdx.x;
    int base = blockIdx.x * 2048 + tid * 8;
    int v[8]; int ts = 0;
#pragma unroll
    for (int r = 0; r < 8; r++) { int i = base + r; int x = (i < total) ? in[i] : 0; v[r] = x; ts += x; }
    lds[tid] = ts;
    __syncthreads();
    for (int off = 1; off < 256; off <<= 1) {
        int t = (tid >= off) ? lds[tid - off] : 0;
        __syncthreads();
        lds[tid] += t;
        __syncthreads();
    }
    int run = lds[tid] - ts;
#pragma unroll
    for (int r = 0; r < 8; r++) { int i = base + r; if (i < total) out[i] = run; run += v[r]; }
    if (tid == 255) bsums[blockIdx.x] = lds[255];
}

__global__ void k_scan2(int* __restrict__ bsums, int nb) {
    if (threadIdx.x == 0 && blockIdx.x == 0) {
        int run = 0;
        for (int i = 0; i < nb; i++) { int t = bsums[i]; bsums[i] = run; run += t; }
    }
}

__global__ __launch_bounds__(256) void k_scan3(const int* __restrict__ pscan, const int* __restrict__ bsums,
                                               int* __restrict__ ptr, int* __restrict__ cursor,
                                               int total, int N) {
    int i = blockIdx.x * 256 + threadIdx.x;
    if (i >= total) return;
    int val = pscan[i] + bsums[i >> 11];
    ptr[i] = val;
    if (i < N) cursor[i] = val;
}

__global__ __launch_bounds__(256) void k_fill(const int* __restrict__ ei, int* __restrict__ cursor,
                                              int* __restrict__ csr, int E) {
    int e = blockIdx.x * 256 + threadIdx.x;
    if (e < E) {
        int src = ei[e];
        int pos = atomicAdd(&cursor[ei[E + e]], 1);
        csr[pos] = src;
    }
}

// ---- MFMA GEMM: C[M,256](bf16) = A[M,256] @ Bt^T, Bt = [256 n-rows][256 k]
__global__ __launch_bounds__(256) void k_gemm(const u16* __restrict__ A, const u16* __restrict__ Bt,
                                              u16* __restrict__ C, int M,
                                              const float* __restrict__ r2, const int* __restrict__ batch) {
    __shared__ __align__(16) u16 As[128 * 64];
    __shared__ __align__(16) u16 Bs[128 * 64];
    const int tid = threadIdx.x;
    const int lane = tid & 63;
    const int wave = tid >> 6;
    const int bm = blockIdx.x >> 1;
    const int bn = blockIdx.x & 1;
    const int m0 = bm * 128, n0 = bn * 128;
    const int wm = wave >> 1, wn = wave & 1;
    const int lm = lane & 15, lq = lane >> 4;
    f32x4 acc[4][4] = {};

    for (int k0 = 0; k0 < 256; k0 += 64) {
        uint4 ra[4], rb[4];
#pragma unroll
        for (int it = 0; it < 4; ++it) {
            int t = tid + 256 * it;
            int m = t >> 3;
            int kc = (t & 7) ^ (m & 7);
            int gm = m0 + m; if (gm > M - 1) gm = M - 1;
            ra[it] = *(const uint4*)(A + (size_t)gm * 256 + k0 + kc * 8);
            rb[it] = *(const uint4*)(Bt + (size_t)(n0 + m) * 256 + k0 + kc * 8);
        }
        __syncthreads();
#pragma unroll
        for (int it = 0; it < 4; ++it) {
            int t = tid + 256 * it;
            *(uint4*)(As + t * 8) = ra[it];
            *(uint4*)(Bs + t * 8) = rb[it];
        }
        __syncthreads();
#pragma unroll
        for (int ks = 0; ks < 2; ++ks) {
            int kq = ks * 4 + lq;
            bf16x8 af[4], bfr[4];
#pragma unroll
            for (int i = 0; i < 4; i++) {
                int m = wm * 64 + i * 16 + lm;
                af[i] = *(const bf16x8*)(As + (m * 8 + (kq ^ (m & 7))) * 8);
                int n = wn * 64 + i * 16 + lm;
                bfr[i] = *(const bf16x8*)(Bs + (n * 8 + (kq ^ (n & 7))) * 8);
            }
#pragma unroll
            for (int i = 0; i < 4; i++)
#pragma unroll
                for (int j = 0; j < 4; j++)
                    acc[i][j] = __builtin_amdgcn_mfma_f32_16x16x32_bf16(af[i], bfr[j], acc[i][j], 0, 0, 0);
        }
    }
#pragma unroll
    for (int i = 0; i < 4; i++) {
#pragma unroll
        for (int r = 0; r < 4; r++) {
            int row = m0 + wm * 64 + i * 16 + lq * 4 + r;
            if (row >= M) continue;
            const float* r2row = r2 ? (r2 + (size_t)batch[row] * 256) : nullptr;
#pragma unroll
            for (int j = 0; j < 4; j++) {
                int col = n0 + wn * 64 + j * 16 + lm;
                float v = acc[i][j][r];
                if (r2row) v += r2row[col];
                C[(size_t)row * 256 + col] = f2b(v);
            }
        }
    }
}

// ---- attention logits ----
__global__ __launch_bounds__(256) void k_al(const u16* __restrict__ h, const u16* __restrict__ a_s,
                                            const u16* __restrict__ a_d,
                                            float* __restrict__ al_s, float* __restrict__ al_d, int N) {
    int node = blockIdx.x * 4 + (threadIdx.x >> 6);
    if (node >= N) return;
    int lane = threadIdx.x & 63;
    int c0 = lane * 4;
    int head = lane >> 4;
    int ci = c0 & 63;
    ushort4 hv = *(const ushort4*)(h + (size_t)node * 256 + c0);
    float h0 = b2f(hv.x), h1 = b2f(hv.y), h2 = b2f(hv.z), h3 = b2f(hv.w);
    ushort4 sv = *(const ushort4*)(a_s + head * 64 + ci);
    ushort4 dv = *(const ushort4*)(a_d + head * 64 + ci);
    float ps = h0 * b2f(sv.x) + h1 * b2f(sv.y) + h2 * b2f(sv.z) + h3 * b2f(sv.w);
    float pd = h0 * b2f(dv.x) + h1 * b2f(dv.y) + h2 * b2f(dv.z) + h3 * b2f(dv.w);
#pragma unroll
    for (int off = 1; off < 16; off <<= 1) { ps += __shfl_xor(ps, off); pd += __shfl_xor(pd, off); }
    if ((lane & 15) == 0) { al_s[node * 4 + head] = ps; al_d[node * 4 + head] = pd; }
}

// ---- fused single-pass aggregation: exp-weighted gather + bias/BN/LN/ReLU (+pool)
// One wave per node. half = lane>>5 selects edge parity; cl = lane&31 owns channels cl*8..cl*8+7.
// No max-subtraction: logits are O(1) here, exp cannot overflow; alpha identical to rounding.
__global__ __launch_bounds__(256) void k_agg3(
    const u16* __restrict__ h, const float* __restrict__ als, const float* __restrict__ ald_,
    const int* __restrict__ ptr, const int* __restrict__ csr,
    const u16* __restrict__ bias, const u16* __restrict__ bng, const u16* __restrict__ bnb,
    const u16* __restrict__ bnm, const u16* __restrict__ bnv,
    const u16* __restrict__ lng, const u16* __restrict__ lnb,
    u16* __restrict__ xout, float* __restrict__ pool, const int* __restrict__ batch, int N) {
    int node = blockIdx.x * 4 + (threadIdx.x >> 6);
    if (node >= N) return;
    int lane = threadIdx.x & 63;
    int half = lane >> 5;
    int cl = lane & 31;
    int c0 = cl * 8;
    int head = cl >> 3;
    int beg = ptr[node], end = ptr[node + 1];
    float ad = ald_[node * 4 + head];

    float acc[8] = {};
    float s = 0.f;
    for (int i0 = beg; i0 < end; i0 += 16) {
#pragma unroll
        for (int u = 0; u < 8; ++u) {
            int e = i0 + 2 * u + half;
            bool valid = (e < end);
            int src = valid ? csr[e] : node;
            float e2 = als[src * 4 + head] + ad;
            e2 = (e2 > 0.f) ? e2 : 0.2f * e2;
            float p = valid ? __expf(e2) : 0.f;
            uint4 rv = *(const uint4*)(h + (size_t)src * 256 + c0);
            s += p;
            acc[0] += p * b2f((u16)(rv.x & 0xffff));
            acc[1] += p * b2f((u16)(rv.x >> 16));
            acc[2] += p * b2f((u16)(rv.y & 0xffff));
            acc[3] += p * b2f((u16)(rv.y >> 16));
            acc[4] += p * b2f((u16)(rv.z & 0xffff));
            acc[5] += p * b2f((u16)(rv.z >> 16));
            acc[6] += p * b2f((u16)(rv.w & 0xffff));
            acc[7] += p * b2f((u16)(rv.w >> 16));
        }
    }
    // combine edge-parity halves (lane <-> lane^32 hold same channels)
#pragma unroll
    for (int j = 0; j < 8; ++j) acc[j] += __shfl_xor(acc[j], 32);
    s += __shfl_xor(s, 32);
    // self loop
    {
        float es = als[node * 4 + head] + ad;
        es = (es > 0.f) ? es : 0.2f * es;
        float ps = __expf(es);
        uint4 rv = *(const uint4*)(h + (size_t)node * 256 + c0);
        s += ps;
        acc[0] += ps * b2f((u16)(rv.x & 0xffff));
        acc[1] += ps * b2f((u16)(rv.x >> 16));
        acc[2] += ps * b2f((u16)(rv.y & 0xffff));
        acc[3] += ps * b2f((u16)(rv.y >> 16));
        acc[4] += ps * b2f((u16)(rv.z & 0xffff));
        acc[5] += ps * b2f((u16)(rv.z >> 16));
        acc[6] += ps * b2f((u16)(rv.w & 0xffff));
        acc[7] += ps * b2f((u16)(rv.w >> 16));
    }
    float inv = 1.0f / (s + 1e-16f);
    // epilogue params: 8 consecutive u16 per array
    uint4 bi = *(const uint4*)(bias + c0);
    uint4 gm = *(const uint4*)(bng + c0);
    uint4 bb = *(const uint4*)(bnb + c0);
    uint4 mm = *(const uint4*)(bnm + c0);
    uint4 vv = *(const uint4*)(bnv + c0);
    uint4 lg = *(const uint4*)(lng + c0);
    uint4 lb = *(const uint4*)(lnb + c0);
    float v[8];
#pragma unroll
    for (int j = 0; j < 8; ++j) {
        u32 w;
        float fbi, fgm, fbb, fmm, fvv;
        w = (&bi.x)[j >> 1]; fbi = b2f((u16)((j & 1) ? (w >> 16) : (w & 0xffff)));
        w = (&gm.x)[j >> 1]; fgm = b2f((u16)((j & 1) ? (w >> 16) : (w & 0xffff)));
        w = (&bb.x)[j >> 1]; fbb = b2f((u16)((j & 1) ? (w >> 16) : (w & 0xffff)));
        w = (&mm.x)[j >> 1]; fmm = b2f((u16)((j & 1) ? (w >> 16) : (w & 0xffff)));
        w = (&vv.x)[j >> 1]; fvv = b2f((u16)((j & 1) ? (w >> 16) : (w & 0xffff)));
        float t = acc[j] * inv + fbi;
        v[j] = (t - fmm) * (fgm * rsqrtf(fvv + 1e-5f)) + fbb;
    }
    // LN over 256 channels; each channel appears in exactly 2 lanes -> divisor 512
    float sum = 0.f;
#pragma unroll
    for (int j = 0; j < 8; ++j) sum += v[j];
#pragma unroll
    for (int off = 1; off < 64; off <<= 1) sum += __shfl_xor(sum, off);
    float mu = sum * (1.0f / 512.0f);
    float q = 0.f;
#pragma unroll
    for (int j = 0; j < 8; ++j) { v[j] -= mu; q += v[j] * v[j]; }
#pragma unroll
    for (int off = 1; off < 64; off <<= 1) q += __shfl_xor(q, off);
    float rstd = rsqrtf(q * (1.0f / 512.0f) + 1e-5f);
    float y[8];
#pragma unroll
    for (int j = 0; j < 8; ++j) {
        u32 w1 = (&lg.x)[j >> 1], w2 = (&lb.x)[j >> 1];
        float flg = b2f((u16)((j & 1) ? (w1 >> 16) : (w1 & 0xffff)));
        float flb = b2f((u16)((j & 1) ? (w2 >> 16) : (w2 & 0xffff)));
        y[j] = fmaxf(v[j] * rstd * flg + flb, 0.f);
    }
    if (half == 0) {
        if (xout) {
            uint4 o;
            o.x = (u32)f2b(y[0]) | ((u32)f2b(y[1]) << 16);
            o.y = (u32)f2b(y[2]) | ((u32)f2b(y[3]) << 16);
            o.z = (u32)f2b(y[4]) | ((u32)f2b(y[5]) << 16);
            o.w = (u32)f2b(y[6]) | ((u32)f2b(y[7]) << 16);
            *(uint4*)(xout + (size_t)node * 256 + c0) = o;
        }
        if (pool) {
            int g = batch[node];
            float* pp = pool + (size_t)g * 256 + c0;
#pragma unroll
            for (int j = 0; j < 8; ++j) atomicAdd(pp + j, y[j]);
        }
    }
}

// ---- r2[b] = x[root_b] @ W2[256:512,:] ----
__global__ __launch_bounds__(256) void k_r2(const u16* __restrict__ xc, const u16* __restrict__ w2,
                                            const int* __restrict__ root, float* __restrict__ r2, int N) {
    __shared__ float xs[256];
    int b = blockIdx.x, c = threadIdx.x;
    int rt = root[b]; if (rt >= N) rt = N - 1; if (rt < 0) rt = 0;
    xs[c] = b2f(xc[(size_t)rt * 256 + c]);
    __syncthreads();
    float acc = 0.f;
    for (int k = 0; k < 256; k++) acc += xs[k] * b2f(w2[(size_t)(256 + k) * 256 + c]);
    r2[b * 256 + c] = acc;
}

// ---- final ----
__global__ void k_final(const float* __restrict__ pool, const u16* __restrict__ x2,
                        const int* __restrict__ root, void* __restrict__ out,
                        const int* __restrict__ flag) {
    int b = blockIdx.x, c = threadIdx.x;
    int r0 = root[b], r1 = root[b + 1];
    int cnt = r1 - r0;
    float inv = 1.0f / (float)(cnt > 1 ? cnt : 1);
    float v0 = pool[b * 256 + c] * inv;
    float v1 = (cnt > 0) ? b2f(x2[(size_t)r0 * 256 + c]) : 0.0f;
    if (*flag) {
        float* o = (float*)out;
        o[b * 512 + c] = v0;
        o[b * 512 + 256 + c] = v1;
    } else {
        u16* o = (u16*)out;
        o[b * 512 + c] = f2b(v0);
        o[b * 512 + 256 + c] = f2b(v1);
    }
}

extern "C" void kernel_launch(void* const* d_in, const int* in_sizes, int n_in,
                              void* d_out, int out_size, void* d_ws, size_t ws_size,
                              hipStream_t stream) {
    u16* outp = (u16*)d_out;
    int ogrid = (out_size + 255) / 256;

    if (n_in != 23) {
        k_sentinel<<<ogrid, 256, 0, stream>>>(outp, out_size, (u16)0x44FA);
        return;
    }

    const void* x_raw = d_in[0];
    const int* ei = (const int*)d_in[1];
    const int* batch = (const int*)d_in[2];
    const int NX = in_sizes[0];
    const int E = in_sizes[1] / 2;
    const int N = in_sizes[2];
    const int NW1 = in_sizes[3];
    const int NW2 = in_sizes[13];
    const int B = NGRAPH;

    char* p = (char*)d_ws;
    auto carve = [&](size_t bytes) -> void* {
        void* r = (void*)p; p += (bytes + 255) & ~(size_t)255; return r;
    };
    u16* xc    = (u16*)carve((size_t)NX * 2);
    u16* w1c   = (u16*)carve((size_t)NW1 * 2);
    u16* w2c   = (u16*)carve((size_t)NW2 * 2);
    u16* sc    = (u16*)carve((size_t)18 * 256 * 2);
    u16* wt1   = (u16*)carve((size_t)65536 * 2);
    u16* wt2   = (u16*)carve((size_t)65536 * 2);
    u16* hbuf  = (u16*)carve((size_t)N * 256 * 2);
    u16* x2    = (u16*)carve((size_t)N * 256 * 2);
    float* als = (float*)carve((size_t)N * 4 * 4);
    float* ald = (float*)carve((size_t)N * 4 * 4);
    int* deg    = (int*)carve((size_t)(N + 1) * 4);
    int* pscan  = (int*)carve((size_t)(N + 1) * 4);
    int* ptr    = (int*)carve((size_t)(N + 1) * 4);
    int* cursor = (int*)carve((size_t)N * 4);
    int* csr    = (int*)carve((size_t)E * 4);
    int* bsums  = (int*)carve(1024);
    int* root   = (int*)carve((size_t)(B + 1) * 4);
    float* r2   = (float*)carve((size_t)B * 256 * 4);
    float* pool = (float*)carve((size_t)B * 256 * 4);
    int* flag   = (int*)carve(256);

    size_t needed = (size_t)(p - (char*)d_ws);
    if (needed > ws_size) {
        k_sentinel<<<ogrid, 256, 0, stream>>>(outp, out_size, (u16)0x447A);
        return;
    }

    k_detect<<<1, 256, 0, stream>>>((const u16*)x_raw, flag);

    int zmax = (N + 1) > (B * 256) ? (N + 1) : (B * 256);
    k_zero<<<(zmax + 255) / 256, 256, 0, stream>>>(deg, pool, N + 1, B * 256);

    k_cvt<<<(NX + 255) / 256, 256, 0, stream>>>(x_raw, xc, NX, flag);
    k_cvt<<<(NW1 + 255) / 256, 256, 0, stream>>>(d_in[3], w1c, NW1, flag);
    k_cvt<<<(NW2 + 255) / 256, 256, 0, stream>>>(d_in[13], w2c, NW2, flag);
    k_cvt_small<<<18, 256, 0, stream>>>(
        d_in[4], d_in[5], d_in[6], d_in[7], d_in[8], d_in[9], d_in[10], d_in[11], d_in[12],
        d_in[14], d_in[15], d_in[16], d_in[17], d_in[18], d_in[19], d_in[20], d_in[21], d_in[22],
        sc, flag);

    k_transpose<<<256, 256, 0, stream>>>(w1c, wt1);
    k_transpose<<<256, 256, 0, stream>>>(w2c, wt2);   // first 256 rows of W2
    k_root<<<1, 256, 0, stream>>>(batch, root, N, B);

    k_hist<<<(E + 255) / 256, 256, 0, stream>>>(ei, deg, E);
    int nb1 = (N + 1 + 2047) / 2048;
    k_scan1<<<nb1, 256, 0, stream>>>(deg, pscan, bsums, N + 1);
    k_scan2<<<1, 64, 0, stream>>>(bsums, nb1);
    k_scan3<<<(N + 1 + 255) / 256, 256, 0, stream>>>(pscan, bsums, ptr, cursor, N + 1, N);
    k_fill<<<(E + 255) / 256, 256, 0, stream>>>(ei, cursor, csr, E);

    int mt = (N + 127) / 128;
    int ngrid = (N + 3) / 4;
    // layer 1
    k_gemm<<<mt * 2, 256, 0, stream>>>(xc, wt1, hbuf, N, nullptr, nullptr);
    k_al<<<ngrid, 256, 0, stream>>>(hbuf, sc + 0 * 256, sc + 1 * 256, als, ald, N);
    k_agg3<<<ngrid, 256, 0, stream>>>(hbuf, als, ald, ptr, csr,
        sc + 2 * 256, sc + 3 * 256, sc + 4 * 256, sc + 5 * 256, sc + 6 * 256, sc + 7 * 256, sc + 8 * 256,
        x2, nullptr, batch, N);
    // layer 2
    k_r2<<<B, 256, 0, stream>>>(xc, w2c, root, r2, N);
    k_gemm<<<mt * 2, 256, 0, stream>>>(x2, wt2, hbuf, N, r2, batch);
    k_al<<<ngrid, 256, 0, stream>>>(hbuf, sc + 9 * 256, sc + 10 * 256, als, ald, N);
    k_agg3<<<ngrid, 256, 0, stream>>>(hbuf, als, ald, ptr, csr,
        sc + 11 * 256, sc + 12 * 256, sc + 13 * 256, sc + 14 * 256, sc + 15 * 256, sc + 16 * 256, sc + 17 * 256,
        nullptr, pool, batch, N);

    k_final<<<B, 256, 0, stream>>>(pool, x2, root, d_out, flag);
    (void)ws_size;
}

// Round 7
// 1060.682 us; speedup vs baseline: 1.0769x; 1.0769x over previous
//
#include <hip/hip_runtime.h>
#include <stdint.h>

typedef unsigned short u16;
typedef unsigned int u32;
typedef unsigned char u8;
typedef __bf16 bf16x8 __attribute__((ext_vector_type(8)));
typedef float f32x4 __attribute__((ext_vector_type(4)));

#define NGRAPH 128

__device__ __forceinline__ float b2f(u16 u) {
    union { u32 i; float f; } c; c.i = ((u32)u) << 16; return c.f;
}
__device__ __forceinline__ u16 f2b(float f) {
    union { float f; u32 i; } c; c.f = f;
    u32 r = c.i + 0x7fffu + ((c.i >> 16) & 1u);
    return (u16)(r >> 16);
}
// extract signed byte k from u32 as float
__device__ __forceinline__ float s8x(u32 v, int k) {
    return (float)((int)(v << (24 - 8 * k)) >> 24);
}

// ---- sentinel (error paths only) ----
__global__ void k_sentinel(u16* __restrict__ out, int n, u16 pat) {
    int i = blockIdx.x * 256 + threadIdx.x;
    if (i < n) out[i] = pat;
}

// ---- fused init: zero deg/pool, dtype detect (block 0), root search (block 1) ----
__global__ __launch_bounds__(256) void k_init(const u16* __restrict__ x, const int* __restrict__ batch,
                                              int* __restrict__ deg, float* __restrict__ pool,
                                              int* __restrict__ flag, int* __restrict__ root,
                                              int N, int B) {
    __shared__ int cnt;
    int i = blockIdx.x * 256 + threadIdx.x;
    if (i < N + 1) deg[i] = 0;
    if (i < B * 256) pool[i] = 0.0f;
    if (blockIdx.x == 0) {
        if (threadIdx.x == 0) cnt = 0;
        __syncthreads();
        int weird = 0;
        for (int k = threadIdx.x; k < 4096; k += 256) {
            u16 u = x[2 * k];                  // fp32 inputs: random low-mantissa halves
            int e = (u >> 7) & 0xff;
            if (e != 0 && (e < 100 || e > 140)) weird++;
        }
        atomicAdd(&cnt, weird);
        __syncthreads();
        if (threadIdx.x == 0) *flag = (cnt > 1024) ? 1 : 0;   // 1 = fp32 inputs
    } else if (blockIdx.x == 1) {
        int b = threadIdx.x;
        if (b <= B) {
            int lo = 0, hi = N;
            while (lo < hi) { int mid = (lo + hi) >> 1; if (batch[mid] < b) lo = mid + 1; else hi = mid; }
            root[b] = lo;
        }
    }
}

// ---- single fused convert: x, W1, W2, 18 small vectors ----
__global__ __launch_bounds__(256) void k_convert(
    const void* __restrict__ x, const void* __restrict__ w1, const void* __restrict__ w2,
    const void* p0, const void* p1, const void* p2, const void* p3, const void* p4,
    const void* p5, const void* p6, const void* p7, const void* p8, const void* p9,
    const void* p10, const void* p11, const void* p12, const void* p13, const void* p14,
    const void* p15, const void* p16, const void* p17,
    u16* __restrict__ xc, u16* __restrict__ w1c, u16* __restrict__ w2c, u16* __restrict__ sc,
    int nx, int nw1, int nw2, const int* __restrict__ flag) {
    const void* ps[18] = {p0,p1,p2,p3,p4,p5,p6,p7,p8,p9,p10,p11,p12,p13,p14,p15,p16,p17};
    int f = *flag;
    long long i = (long long)blockIdx.x * 256 + threadIdx.x;
    long long t0 = nx, t1 = t0 + nw1, t2 = t1 + nw2, t3 = t2 + 18 * 256;
    if (i < t0) {
        xc[i] = f ? f2b(((const float*)x)[i]) : ((const u16*)x)[i];
    } else if (i < t1) {
        long long j = i - t0;
        w1c[j] = f ? f2b(((const float*)w1)[j]) : ((const u16*)w1)[j];
    } else if (i < t2) {
        long long j = i - t1;
        w2c[j] = f ? f2b(((const float*)w2)[j]) : ((const u16*)w2)[j];
    } else if (i < t3) {
        long long k = i - t2;
        const void* s = ps[k >> 8];
        int j = (int)(k & 255);
        sc[k] = f ? f2b(((const float*)s)[j]) : ((const u16*)s)[j];
    }
}

// ---- dual transpose 256x256 ----
__global__ __launch_bounds__(256) void k_tr2(const u16* __restrict__ w1, u16* __restrict__ wt1,
                                             const u16* __restrict__ w2, u16* __restrict__ wt2) {
    int idx = blockIdx.x * 256 + threadIdx.x;
    int halfsel = idx >> 16;
    int j = idx & 65535;
    int n = j >> 8, k = j & 255;
    if (halfsel == 0) wt1[n * 256 + k] = w1[k * 256 + n];
    else              wt2[n * 256 + k] = w2[k * 256 + n];
}

__global__ __launch_bounds__(256) void k_hist(const int* __restrict__ ei, int* __restrict__ deg, int E) {
    int e = blockIdx.x * 256 + threadIdx.x;
    if (e < E) atomicAdd(&deg[ei[E + e]], 1);
}

__global__ __launch_bounds__(256) void k_scan1(const int* __restrict__ in, int* __restrict__ out,
                                               int* __restrict__ bsums, int total) {
    __shared__ int lds[256];
    int tid = threadIdx.x;
    int base = blockIdx.x * 2048 + tid * 8;
    int v[8]; int ts = 0;
#pragma unroll
    for (int r = 0; r < 8; r++) { int i = base + r; int x = (i < total) ? in[i] : 0; v[r] = x; ts += x; }
    lds[tid] = ts;
    __syncthreads();
    for (int off = 1; off < 256; off <<= 1) {
        int t = (tid >= off) ? lds[tid - off] : 0;
        __syncthreads();
        lds[tid] += t;
        __syncthreads();
    }
    int run = lds[tid] - ts;
#pragma unroll
    for (int r = 0; r < 8; r++) { int i = base + r; if (i < total) out[i] = run; run += v[r]; }
    if (tid == 255) bsums[blockIdx.x] = lds[255];
}

__global__ void k_scan2(int* __restrict__ bsums, int nb) {
    if (threadIdx.x == 0 && blockIdx.x == 0) {
        int run = 0;
        for (int i = 0; i < nb; i++) { int t = bsums[i]; bsums[i] = run; run += t; }
    }
}

__global__ __launch_bounds__(256) void k_scan3(const int* __restrict__ pscan, const int* __restrict__ bsums,
                                               int* __restrict__ ptr, int* __restrict__ cursor,
                                               int total, int N) {
    int i = blockIdx.x * 256 + threadIdx.x;
    if (i >= total) return;
    int val = pscan[i] + bsums[i >> 11];
    ptr[i] = val;
    if (i < N) cursor[i] = val;
}

__global__ __launch_bounds__(256) void k_fill(const int* __restrict__ ei, int* __restrict__ cursor,
                                              int* __restrict__ csr, int E) {
    int e = blockIdx.x * 256 + threadIdx.x;
    if (e < E) {
        int src = ei[e];
        int pos = atomicAdd(&cursor[ei[E + e]], 1);
        csr[pos] = src;
    }
}

// ---- MFMA GEMM: C[M,256](bf16) = A[M,256] @ Bt^T, Bt = [256 n-rows][256 k]
// epilogue: optional += r2[batch[row]][col]; writes bf16 C, per-row-per-head-scaled int8 C8
// (coalesced via LDS), and scale into salsc[row*8 + head*2 + 1].
__global__ __launch_bounds__(256) void k_gemm(const u16* __restrict__ A, const u16* __restrict__ Bt,
                                              u16* __restrict__ C, u8* __restrict__ C8,
                                              float* __restrict__ salsc, int M,
                                              const float* __restrict__ r2, const int* __restrict__ batch) {
    __shared__ __align__(16) u16 smem[128 * 64 * 2];
    u16* As = smem;
    u16* Bs = smem + 128 * 64;
    const int tid = threadIdx.x;
    const int lane = tid & 63;
    const int wave = tid >> 6;
    const int bm = blockIdx.x >> 1;
    const int bn = blockIdx.x & 1;
    const int m0 = bm * 128, n0 = bn * 128;
    const int wm = wave >> 1, wn = wave & 1;
    const int lm = lane & 15, lq = lane >> 4;
    f32x4 acc[4][4] = {};

    for (int k0 = 0; k0 < 256; k0 += 64) {
        uint4 ra[4], rb[4];
#pragma unroll
        for (int it = 0; it < 4; ++it) {
            int t = tid + 256 * it;
            int m = t >> 3;
            int kc = (t & 7) ^ (m & 7);
            int gm = m0 + m; if (gm > M - 1) gm = M - 1;
            ra[it] = *(const uint4*)(A + (size_t)gm * 256 + k0 + kc * 8);
            rb[it] = *(const uint4*)(Bt + (size_t)(n0 + m) * 256 + k0 + kc * 8);
        }
        __syncthreads();
#pragma unroll
        for (int it = 0; it < 4; ++it) {
            int t = tid + 256 * it;
            *(uint4*)(As + t * 8) = ra[it];
            *(uint4*)(Bs + t * 8) = rb[it];
        }
        __syncthreads();
#pragma unroll
        for (int ks = 0; ks < 2; ++ks) {
            int kq = ks * 4 + lq;
            bf16x8 af[4], bfr[4];
#pragma unroll
            for (int i = 0; i < 4; i++) {
                int m = wm * 64 + i * 16 + lm;
                af[i] = *(const bf16x8*)(As + (m * 8 + (kq ^ (m & 7))) * 8);
                int n = wn * 64 + i * 16 + lm;
                bfr[i] = *(const bf16x8*)(Bs + (n * 8 + (kq ^ (n & 7))) * 8);
            }
#pragma unroll
            for (int i = 0; i < 4; i++)
#pragma unroll
                for (int j = 0; j < 4; j++)
                    acc[i][j] = __builtin_amdgcn_mfma_f32_16x16x32_bf16(af[i], bfr[j], acc[i][j], 0, 0, 0);
        }
    }

    __syncthreads();                       // done with As/Bs; reuse as int8 tile
    u8* lds8 = (u8*)smem;                  // 128 rows x 144-padded (18432 B)
#pragma unroll
    for (int i = 0; i < 4; i++) {
#pragma unroll
        for (int r = 0; r < 4; r++) {
            int rl = wm * 64 + i * 16 + lq * 4 + r;
            int row = m0 + rl;
            bool ok = (row < M);
            const float* r2row = (r2 && ok) ? (r2 + (size_t)batch[row] * 256) : nullptr;
            float v[4];
#pragma unroll
            for (int j = 0; j < 4; j++) {
                v[j] = acc[i][j][r];
                if (r2row) v[j] += r2row[n0 + wn * 64 + j * 16 + lm];
            }
            float mx = fmaxf(fmaxf(fabsf(v[0]), fabsf(v[1])), fmaxf(fabsf(v[2]), fabsf(v[3])));
#pragma unroll
            for (int off = 1; off < 16; off <<= 1) mx = fmaxf(mx, __shfl_xor(mx, off));
            float scl = mx * (1.0f / 127.0f);
            float isc = (mx > 0.f) ? 127.0f / mx : 0.f;
#pragma unroll
            for (int j = 0; j < 4; j++) {
                int col = n0 + wn * 64 + j * 16 + lm;
                if (ok) C[(size_t)row * 256 + col] = f2b(v[j]);
                int q = (int)rintf(v[j] * isc);
                lds8[rl * 144 + wn * 64 + j * 16 + lm] = (u8)(q & 0xff);
            }
            if (ok && lm == 0) salsc[(size_t)row * 8 + (bn * 2 + wn) * 2 + 1] = scl;
        }
    }
    __syncthreads();
    for (int t = tid; t < 1024; t += 256) {      // 128 rows x 8 x 16B
        int rl = t >> 3;
        int off = (t & 7) * 16;
        int row = m0 + rl;
        if (row < M)
            *(uint4*)(C8 + (size_t)row * 256 + n0 + off) = *(const uint4*)(lds8 + rl * 144 + off);
    }
}

// ---- attention logits -> salsc (als) + ald ----
__global__ __launch_bounds__(256) void k_al(const u16* __restrict__ h, const u16* __restrict__ a_s,
                                            const u16* __restrict__ a_d,
                                            float* __restrict__ salsc, float* __restrict__ ald, int N) {
    int node = blockIdx.x * 4 + (threadIdx.x >> 6);
    if (node >= N) return;
    int lane = threadIdx.x & 63;
    int c0 = lane * 4;
    int head = lane >> 4;
    int ci = c0 & 63;
    ushort4 hv = *(const ushort4*)(h + (size_t)node * 256 + c0);
    float h0 = b2f(hv.x), h1 = b2f(hv.y), h2 = b2f(hv.z), h3 = b2f(hv.w);
    ushort4 sv = *(const ushort4*)(a_s + head * 64 + ci);
    ushort4 dv = *(const ushort4*)(a_d + head * 64 + ci);
    float ps = h0 * b2f(sv.x) + h1 * b2f(sv.y) + h2 * b2f(sv.z) + h3 * b2f(sv.w);
    float pd = h0 * b2f(dv.x) + h1 * b2f(dv.y) + h2 * b2f(dv.z) + h3 * b2f(dv.w);
#pragma unroll
    for (int off = 1; off < 16; off <<= 1) { ps += __shfl_xor(ps, off); pd += __shfl_xor(pd, off); }
    if ((lane & 15) == 0) {
        salsc[(size_t)node * 8 + head * 2] = ps;
        ald[node * 4 + head] = pd;
    }
}

// ---- fused aggregation: no-max softmax, scaled-int8 value gather (256 B/row),
// bf16 self row, bias/BN/LN/ReLU epilogue (+pool). One wave per node.
__global__ __launch_bounds__(256) void k_agg5(
    const u16* __restrict__ h, const u8* __restrict__ h8,
    const float* __restrict__ salsc, const float* __restrict__ ald_,
    const int* __restrict__ ptr, const int* __restrict__ csr,
    const u16* __restrict__ bias, const u16* __restrict__ bng, const u16* __restrict__ bnb,
    const u16* __restrict__ bnm, const u16* __restrict__ bnv,
    const u16* __restrict__ lng, const u16* __restrict__ lnb,
    u16* __restrict__ xout, float* __restrict__ pool, const int* __restrict__ batch, int N) {
    int node = blockIdx.x * 4 + (threadIdx.x >> 6);
    if (node >= N) return;
    int lane = threadIdx.x & 63;
    int c0 = lane * 4;
    int head = lane >> 4;
    float ad = ald_[node * 4 + head];
    // self loop (exact bf16 values)
    float es = salsc[(size_t)node * 8 + head * 2] + ad; es = (es > 0.f) ? es : 0.2f * es;
    float psf = __expf(es);
    float s = psf;
    ushort4 hv = *(const ushort4*)(h + (size_t)node * 256 + c0);
    float a0 = psf * b2f(hv.x), a1 = psf * b2f(hv.y), a2 = psf * b2f(hv.z), a3 = psf * b2f(hv.w);
    int beg = ptr[node], end = ptr[node + 1];
    int i = beg;
    for (; i + 4 <= end; i += 4) {
        int s0 = csr[i], s1 = csr[i + 1], s2 = csr[i + 2], s3 = csr[i + 3];
        float2 f0 = *(const float2*)(salsc + (size_t)s0 * 8 + head * 2);
        float2 f1 = *(const float2*)(salsc + (size_t)s1 * 8 + head * 2);
        float2 f2v = *(const float2*)(salsc + (size_t)s2 * 8 + head * 2);
        float2 f3 = *(const float2*)(salsc + (size_t)s3 * 8 + head * 2);
        u32 r0 = *(const u32*)(h8 + (size_t)s0 * 256 + c0);
        u32 r1 = *(const u32*)(h8 + (size_t)s1 * 256 + c0);
        u32 r2v = *(const u32*)(h8 + (size_t)s2 * 256 + c0);
        u32 r3 = *(const u32*)(h8 + (size_t)s3 * 256 + c0);
        float e0 = f0.x + ad; e0 = (e0 > 0.f) ? e0 : 0.2f * e0;
        float e1 = f1.x + ad; e1 = (e1 > 0.f) ? e1 : 0.2f * e1;
        float e2 = f2v.x + ad; e2 = (e2 > 0.f) ? e2 : 0.2f * e2;
        float e3 = f3.x + ad; e3 = (e3 > 0.f) ? e3 : 0.2f * e3;
        float p0 = __expf(e0), p1 = __expf(e1), p2 = __expf(e2), p3 = __expf(e3);
        s += p0 + p1 + p2 + p3;
        float w0 = p0 * f0.y, w1 = p1 * f1.y, w2 = p2 * f2v.y, w3 = p3 * f3.y;
        a0 += w0 * s8x(r0, 0) + w1 * s8x(r1, 0) + w2 * s8x(r2v, 0) + w3 * s8x(r3, 0);
        a1 += w0 * s8x(r0, 1) + w1 * s8x(r1, 1) + w2 * s8x(r2v, 1) + w3 * s8x(r3, 1);
        a2 += w0 * s8x(r0, 2) + w1 * s8x(r1, 2) + w2 * s8x(r2v, 2) + w3 * s8x(r3, 2);
        a3 += w0 * s8x(r0, 3) + w1 * s8x(r1, 3) + w2 * s8x(r2v, 3) + w3 * s8x(r3, 3);
    }
    for (; i < end; ++i) {
        int s0 = csr[i];
        float2 f0 = *(const float2*)(salsc + (size_t)s0 * 8 + head * 2);
        u32 r0 = *(const u32*)(h8 + (size_t)s0 * 256 + c0);
        float e0 = f0.x + ad; e0 = (e0 > 0.f) ? e0 : 0.2f * e0;
        float p0 = __expf(e0);
        s += p0;
        float w0 = p0 * f0.y;
        a0 += w0 * s8x(r0, 0); a1 += w0 * s8x(r0, 1); a2 += w0 * s8x(r0, 2); a3 += w0 * s8x(r0, 3);
    }
    float inv = 1.0f / (s + 1e-16f);
    float v0 = a0 * inv + b2f(bias[c0 + 0]);
    float v1 = a1 * inv + b2f(bias[c0 + 1]);
    float v2 = a2 * inv + b2f(bias[c0 + 2]);
    float v3 = a3 * inv + b2f(bias[c0 + 3]);
    v0 = (v0 - b2f(bnm[c0 + 0])) * (b2f(bng[c0 + 0]) * rsqrtf(b2f(bnv[c0 + 0]) + 1e-5f)) + b2f(bnb[c0 + 0]);
    v1 = (v1 - b2f(bnm[c0 + 1])) * (b2f(bng[c0 + 1]) * rsqrtf(b2f(bnv[c0 + 1]) + 1e-5f)) + b2f(bnb[c0 + 1]);
    v2 = (v2 - b2f(bnm[c0 + 2])) * (b2f(bng[c0 + 2]) * rsqrtf(b2f(bnv[c0 + 2]) + 1e-5f)) + b2f(bnb[c0 + 2]);
    v3 = (v3 - b2f(bnm[c0 + 3])) * (b2f(bng[c0 + 3]) * rsqrtf(b2f(bnv[c0 + 3]) + 1e-5f)) + b2f(bnb[c0 + 3]);
    float sum = v0 + v1 + v2 + v3;
#pragma unroll
    for (int off = 1; off < 64; off <<= 1) sum += __shfl_xor(sum, off);
    float mu = sum * 0.00390625f;
    float d0 = v0 - mu, d1 = v1 - mu, d2 = v2 - mu, d3 = v3 - mu;
    float q = d0 * d0 + d1 * d1 + d2 * d2 + d3 * d3;
#pragma unroll
    for (int off = 1; off < 64; off <<= 1) q += __shfl_xor(q, off);
    float rstd = rsqrtf(q * 0.00390625f + 1e-5f);
    float y0 = fmaxf(d0 * rstd * b2f(lng[c0 + 0]) + b2f(lnb[c0 + 0]), 0.f);
    float y1 = fmaxf(d1 * rstd * b2f(lng[c0 + 1]) + b2f(lnb[c0 + 1]), 0.f);
    float y2 = fmaxf(d2 * rstd * b2f(lng[c0 + 2]) + b2f(lnb[c0 + 2]), 0.f);
    float y3 = fmaxf(d3 * rstd * b2f(lng[c0 + 3]) + b2f(lnb[c0 + 3]), 0.f);
    if (xout) {
        uint2 o;
        o.x = (u32)f2b(y0) | ((u32)f2b(y1) << 16);
        o.y = (u32)f2b(y2) | ((u32)f2b(y3) << 16);
        *(uint2*)(xout + (size_t)node * 256 + c0) = o;
    }
    if (pool) {
        int g = batch[node];
        float* pp = pool + (size_t)g * 256 + c0;
        atomicAdd(pp + 0, y0); atomicAdd(pp + 1, y1); atomicAdd(pp + 2, y2); atomicAdd(pp + 3, y3);
    }
}

// ---- r2[b] = x[root_b] @ W2[256:512,:] ----
__global__ __launch_bounds__(256) void k_r2(const u16* __restrict__ xc, const u16* __restrict__ w2,
                                            const int* __restrict__ root, float* __restrict__ r2, int N) {
    __shared__ float xs[256];
    int b = blockIdx.x, c = threadIdx.x;
    int rt = root[b]; if (rt >= N) rt = N - 1; if (rt < 0) rt = 0;
    xs[c] = b2f(xc[(size_t)rt * 256 + c]);
    __syncthreads();
    float acc = 0.f;
    for (int k = 0; k < 256; k++) acc += xs[k] * b2f(w2[(size_t)(256 + k) * 256 + c]);
    r2[b * 256 + c] = acc;
}

// ---- final ----
__global__ void k_final(const float* __restrict__ pool, const u16* __restrict__ x2,
                        const int* __restrict__ root, void* __restrict__ out,
                        const int* __restrict__ flag) {
    int b = blockIdx.x, c = threadIdx.x;
    int r0 = root[b], r1 = root[b + 1];
    int cnt = r1 - r0;
    float inv = 1.0f / (float)(cnt > 1 ? cnt : 1);
    float v0 = pool[b * 256 + c] * inv;
    float v1 = (cnt > 0) ? b2f(x2[(size_t)r0 * 256 + c]) : 0.0f;
    if (*flag) {
        float* o = (float*)out;
        o[b * 512 + c] = v0;
        o[b * 512 + 256 + c] = v1;
    } else {
        u16* o = (u16*)out;
        o[b * 512 + c] = f2b(v0);
        o[b * 512 + 256 + c] = f2b(v1);
    }
}

extern "C" void kernel_launch(void* const* d_in, const int* in_sizes, int n_in,
                              void* d_out, int out_size, void* d_ws, size_t ws_size,
                              hipStream_t stream) {
    u16* outp = (u16*)d_out;
    int ogrid = (out_size + 255) / 256;

    if (n_in != 23) {
        k_sentinel<<<ogrid, 256, 0, stream>>>(outp, out_size, (u16)0x44FA);
        return;
    }

    const void* x_raw = d_in[0];
    const int* ei = (const int*)d_in[1];
    const int* batch = (const int*)d_in[2];
    const int NX = in_sizes[0];
    const int E = in_sizes[1] / 2;
    const int N = in_sizes[2];
    const int NW1 = in_sizes[3];
    const int NW2 = in_sizes[13];
    const int B = NGRAPH;

    char* p = (char*)d_ws;
    auto carve = [&](size_t bytes) -> void* {
        void* r = (void*)p; p += (bytes + 255) & ~(size_t)255; return r;
    };
    u16* xc    = (u16*)carve((size_t)NX * 2);
    u16* w1c   = (u16*)carve((size_t)NW1 * 2);
    u16* w2c   = (u16*)carve((size_t)NW2 * 2);
    u16* sc    = (u16*)carve((size_t)18 * 256 * 2);
    u16* wt1   = (u16*)carve((size_t)65536 * 2);
    u16* wt2   = (u16*)carve((size_t)65536 * 2);
    u16* hbuf  = (u16*)carve((size_t)N * 256 * 2);
    u8*  h8    = (u8*)carve((size_t)N * 256);
    u16* x2    = (u16*)carve((size_t)N * 256 * 2);
    float* salsc = (float*)carve((size_t)N * 8 * 4);
    float* ald = (float*)carve((size_t)N * 4 * 4);
    int* deg    = (int*)carve((size_t)(N + 1) * 4);
    int* pscan  = (int*)carve((size_t)(N + 1) * 4);
    int* ptr    = (int*)carve((size_t)(N + 1) * 4);
    int* cursor = (int*)carve((size_t)N * 4);
    int* csr    = (int*)carve((size_t)E * 4);
    int* bsums  = (int*)carve(1024);
    int* root   = (int*)carve((size_t)(B + 1) * 4);
    float* r2   = (float*)carve((size_t)B * 256 * 4);
    float* pool = (float*)carve((size_t)B * 256 * 4);
    int* flag   = (int*)carve(256);

    size_t needed = (size_t)(p - (char*)d_ws);
    if (needed > ws_size) {
        k_sentinel<<<ogrid, 256, 0, stream>>>(outp, out_size, (u16)0x447A);
        return;
    }

    int zmax = (N + 1) > (B * 256) ? (N + 1) : (B * 256);
    k_init<<<(zmax + 255) / 256, 256, 0, stream>>>((const u16*)x_raw, batch, deg, pool, flag, root, N, B);

    long long tot = (long long)NX + NW1 + NW2 + 18 * 256;
    k_convert<<<(unsigned)((tot + 255) / 256), 256, 0, stream>>>(
        x_raw, d_in[3], d_in[13],
        d_in[4], d_in[5], d_in[6], d_in[7], d_in[8], d_in[9], d_in[10], d_in[11], d_in[12],
        d_in[14], d_in[15], d_in[16], d_in[17], d_in[18], d_in[19], d_in[20], d_in[21], d_in[22],
        xc, w1c, w2c, sc, NX, NW1, NW2, flag);

    k_tr2<<<512, 256, 0, stream>>>(w1c, wt1, w2c, wt2);

    k_hist<<<(E + 255) / 256, 256, 0, stream>>>(ei, deg, E);
    int nb1 = (N + 1 + 2047) / 2048;
    k_scan1<<<nb1, 256, 0, stream>>>(deg, pscan, bsums, N + 1);
    k_scan2<<<1, 64, 0, stream>>>(bsums, nb1);
    k_scan3<<<(N + 1 + 255) / 256, 256, 0, stream>>>(pscan, bsums, ptr, cursor, N + 1, N);
    k_fill<<<(E + 255) / 256, 256, 0, stream>>>(ei, cursor, csr, E);

    int mt = (N + 127) / 128;
    int ngrid = (N + 3) / 4;
    // layer 1
    k_gemm<<<mt * 2, 256, 0, stream>>>(xc, wt1, hbuf, h8, salsc, N, nullptr, nullptr);
    k_al<<<ngrid, 256, 0, stream>>>(hbuf, sc + 0 * 256, sc + 1 * 256, salsc, ald, N);
    k_agg5<<<ngrid, 256, 0, stream>>>(hbuf, h8, salsc, ald, ptr, csr,
        sc + 2 * 256, sc + 3 * 256, sc + 4 * 256, sc + 5 * 256, sc + 6 * 256, sc + 7 * 256, sc + 8 * 256,
        x2, nullptr, batch, N);
    // layer 2
    k_r2<<<B, 256, 0, stream>>>(xc, w2c, root, r2, N);
    k_gemm<<<mt * 2, 256, 0, stream>>>(x2, wt2, hbuf, h8, salsc, N, r2, batch);
    k_al<<<ngrid, 256, 0, stream>>>(hbuf, sc + 9 * 256, sc + 10 * 256, salsc, ald, N);
    k_agg5<<<ngrid, 256, 0, stream>>>(hbuf, h8, salsc, ald, ptr, csr,
        sc + 11 * 256, sc + 12 * 256, sc + 13 * 256, sc + 14 * 256, sc + 15 * 256, sc + 16 * 256, sc + 17 * 256,
        nullptr, pool, batch, N);

    k_final<<<B, 256, 0, stream>>>(pool, x2, root, d_out, flag);
    (void)ws_size;
}

// Round 8
// 725.980 us; speedup vs baseline: 1.5733x; 1.4610x over previous
//
#include <hip/hip_runtime.h>
#include <stdint.h>

typedef unsigned short u16;
typedef unsigned int u32;
typedef unsigned char u8;
typedef __bf16 bf16x8 __attribute__((ext_vector_type(8)));
typedef float f32x4 __attribute__((ext_vector_type(4)));

#define NGRAPH 128

__device__ __forceinline__ float b2f(u16 u) {
    union { u32 i; float f; } c; c.i = ((u32)u) << 16; return c.f;
}
__device__ __forceinline__ u16 f2b(float f) {
    union { float f; u32 i; } c; c.f = f;
    u32 r = c.i + 0x7fffu + ((c.i >> 16) & 1u);
    return (u16)(r >> 16);
}
// extract signed byte k from u32 as float
__device__ __forceinline__ float s8x(u32 v, int k) {
    return (float)((int)(v << (24 - 8 * k)) >> 24);
}

// ---- sentinel (error paths only) ----
__global__ void k_sentinel(u16* __restrict__ out, int n, u16 pat) {
    int i = blockIdx.x * 256 + threadIdx.x;
    if (i < n) out[i] = pat;
}

// ---- fused init: zero deg/pool, dtype detect (block 0), root search (block 1) ----
__global__ __launch_bounds__(256) void k_init(const u16* __restrict__ x, const int* __restrict__ batch,
                                              int* __restrict__ deg, float* __restrict__ pool,
                                              int* __restrict__ flag, int* __restrict__ root,
                                              int N, int B) {
    __shared__ int cnt;
    int i = blockIdx.x * 256 + threadIdx.x;
    if (i < N + 1) deg[i] = 0;
    if (i < B * 256) pool[i] = 0.0f;
    if (blockIdx.x == 0) {
        if (threadIdx.x == 0) cnt = 0;
        __syncthreads();
        int weird = 0;
        for (int k = threadIdx.x; k < 4096; k += 256) {
            u16 u = x[2 * k];                  // fp32 inputs: random low-mantissa halves
            int e = (u >> 7) & 0xff;
            if (e != 0 && (e < 100 || e > 140)) weird++;
        }
        atomicAdd(&cnt, weird);
        __syncthreads();
        if (threadIdx.x == 0) *flag = (cnt > 1024) ? 1 : 0;   // 1 = fp32 inputs
    } else if (blockIdx.x == 1) {
        int b = threadIdx.x;
        if (b <= B) {
            int lo = 0, hi = N;
            while (lo < hi) { int mid = (lo + hi) >> 1; if (batch[mid] < b) lo = mid + 1; else hi = mid; }
            root[b] = lo;
        }
    }
}

// ---- vectorized convert (4 elements/thread, no private arrays -> no scratch) ----
__global__ __launch_bounds__(256) void k_cvt4(const void* __restrict__ src, u16* __restrict__ dst,
                                              int n4, const int* __restrict__ flag) {
    int i = blockIdx.x * 256 + threadIdx.x;
    if (i >= n4) return;
    if (*flag) {
        float4 v = ((const float4*)src)[i];
        ushort4 o;
        o.x = f2b(v.x); o.y = f2b(v.y); o.z = f2b(v.z); o.w = f2b(v.w);
        ((ushort4*)dst)[i] = o;
    } else {
        ((ushort4*)dst)[i] = ((const ushort4*)src)[i];
    }
}

// ---- small-vector convert: 18 blocks x 256 (tiny; private ptr array harmless here) ----
__global__ __launch_bounds__(256) void k_cvt_small(
    const void* p0, const void* p1, const void* p2, const void* p3, const void* p4,
    const void* p5, const void* p6, const void* p7, const void* p8, const void* p9,
    const void* p10, const void* p11, const void* p12, const void* p13, const void* p14,
    const void* p15, const void* p16, const void* p17,
    u16* __restrict__ dst, const int* __restrict__ flag) {
    const void* ps[18] = {p0,p1,p2,p3,p4,p5,p6,p7,p8,p9,p10,p11,p12,p13,p14,p15,p16,p17};
    int f = *flag;
    int vec = blockIdx.x;
    int j = threadIdx.x;
    const void* s = ps[vec];
    dst[vec * 256 + j] = f ? f2b(((const float*)s)[j]) : ((const u16*)s)[j];
}

// ---- dual transpose 256x256 ----
__global__ __launch_bounds__(256) void k_tr2(const u16* __restrict__ w1, u16* __restrict__ wt1,
                                             const u16* __restrict__ w2, u16* __restrict__ wt2) {
    int idx = blockIdx.x * 256 + threadIdx.x;
    int halfsel = idx >> 16;
    int j = idx & 65535;
    int n = j >> 8, k = j & 255;
    if (halfsel == 0) wt1[n * 256 + k] = w1[k * 256 + n];
    else              wt2[n * 256 + k] = w2[k * 256 + n];
}

__global__ __launch_bounds__(256) void k_hist(const int* __restrict__ ei, int* __restrict__ deg, int E) {
    int e = blockIdx.x * 256 + threadIdx.x;
    if (e < E) atomicAdd(&deg[ei[E + e]], 1);
}

__global__ __launch_bounds__(256) void k_scan1(const int* __restrict__ in, int* __restrict__ out,
                                               int* __restrict__ bsums, int total) {
    __shared__ int lds[256];
    int tid = threadIdx.x;
    int base = blockIdx.x * 2048 + tid * 8;
    int v[8]; int ts = 0;
#pragma unroll
    for (int r = 0; r < 8; r++) { int i = base + r; int x = (i < total) ? in[i] : 0; v[r] = x; ts += x; }
    lds[tid] = ts;
    __syncthreads();
    for (int off = 1; off < 256; off <<= 1) {
        int t = (tid >= off) ? lds[tid - off] : 0;
        __syncthreads();
        lds[tid] += t;
        __syncthreads();
    }
    int run = lds[tid] - ts;
#pragma unroll
    for (int r = 0; r < 8; r++) { int i = base + r; if (i < total) out[i] = run; run += v[r]; }
    if (tid == 255) bsums[blockIdx.x] = lds[255];
}

__global__ void k_scan2(int* __restrict__ bsums, int nb) {
    if (threadIdx.x == 0 && blockIdx.x == 0) {
        int run = 0;
        for (int i = 0; i < nb; i++) { int t = bsums[i]; bsums[i] = run; run += t; }
    }
}

__global__ __launch_bounds__(256) void k_scan3(const int* __restrict__ pscan, const int* __restrict__ bsums,
                                               int* __restrict__ ptr, int* __restrict__ cursor,
                                               int total, int N) {
    int i = blockIdx.x * 256 + threadIdx.x;
    if (i >= total) return;
    int val = pscan[i] + bsums[i >> 11];
    ptr[i] = val;
    if (i < N) cursor[i] = val;
}

__global__ __launch_bounds__(256) void k_fill(const int* __restrict__ ei, int* __restrict__ cursor,
                                              int* __restrict__ csr, int E) {
    int e = blockIdx.x * 256 + threadIdx.x;
    if (e < E) {
        int src = ei[e];
        int pos = atomicAdd(&cursor[ei[E + e]], 1);
        csr[pos] = src;
    }
}

// ---- MFMA GEMM: C[M,256](bf16) = A[M,256] @ Bt^T, Bt = [256 n-rows][256 k]
// epilogue: optional += r2[batch[row]][col]; writes bf16 C, per-row-per-head-scaled int8 C8
// (coalesced via LDS), and scale into salsc[row*8 + head*2 + 1].
__global__ __launch_bounds__(256) void k_gemm(const u16* __restrict__ A, const u16* __restrict__ Bt,
                                              u16* __restrict__ C, u8* __restrict__ C8,
                                              float* __restrict__ salsc, int M,
                                              const float* __restrict__ r2, const int* __restrict__ batch) {
    __shared__ __align__(16) u16 smem[128 * 64 * 2];
    u16* As = smem;
    u16* Bs = smem + 128 * 64;
    const int tid = threadIdx.x;
    const int lane = tid & 63;
    const int wave = tid >> 6;
    const int bm = blockIdx.x >> 1;
    const int bn = blockIdx.x & 1;
    const int m0 = bm * 128, n0 = bn * 128;
    const int wm = wave >> 1, wn = wave & 1;
    const int lm = lane & 15, lq = lane >> 4;
    f32x4 acc[4][4] = {};

    for (int k0 = 0; k0 < 256; k0 += 64) {
        uint4 ra[4], rb[4];
#pragma unroll
        for (int it = 0; it < 4; ++it) {
            int t = tid + 256 * it;
            int m = t >> 3;
            int kc = (t & 7) ^ (m & 7);
            int gm = m0 + m; if (gm > M - 1) gm = M - 1;
            ra[it] = *(const uint4*)(A + (size_t)gm * 256 + k0 + kc * 8);
            rb[it] = *(const uint4*)(Bt + (size_t)(n0 + m) * 256 + k0 + kc * 8);
        }
        __syncthreads();
#pragma unroll
        for (int it = 0; it < 4; ++it) {
            int t = tid + 256 * it;
            *(uint4*)(As + t * 8) = ra[it];
            *(uint4*)(Bs + t * 8) = rb[it];
        }
        __syncthreads();
#pragma unroll
        for (int ks = 0; ks < 2; ++ks) {
            int kq = ks * 4 + lq;
            bf16x8 af[4], bfr[4];
#pragma unroll
            for (int i = 0; i < 4; i++) {
                int m = wm * 64 + i * 16 + lm;
                af[i] = *(const bf16x8*)(As + (m * 8 + (kq ^ (m & 7))) * 8);
                int n = wn * 64 + i * 16 + lm;
                bfr[i] = *(const bf16x8*)(Bs + (n * 8 + (kq ^ (n & 7))) * 8);
            }
#pragma unroll
            for (int i = 0; i < 4; i++)
#pragma unroll
                for (int j = 0; j < 4; j++)
                    acc[i][j] = __builtin_amdgcn_mfma_f32_16x16x32_bf16(af[i], bfr[j], acc[i][j], 0, 0, 0);
        }
    }

    __syncthreads();                       // done with As/Bs; reuse as int8 tile
    u8* lds8 = (u8*)smem;                  // 128 rows x 144-padded (18432 B)
#pragma unroll
    for (int i = 0; i < 4; i++) {
#pragma unroll
        for (int r = 0; r < 4; r++) {
            int rl = wm * 64 + i * 16 + lq * 4 + r;
            int row = m0 + rl;
            bool ok = (row < M);
            const float* r2row = (r2 && ok) ? (r2 + (size_t)batch[row] * 256) : nullptr;
            float v[4];
#pragma unroll
            for (int j = 0; j < 4; j++) {
                v[j] = acc[i][j][r];
                if (r2row) v[j] += r2row[n0 + wn * 64 + j * 16 + lm];
            }
            float mx = fmaxf(fmaxf(fabsf(v[0]), fabsf(v[1])), fmaxf(fabsf(v[2]), fabsf(v[3])));
#pragma unroll
            for (int off = 1; off < 16; off <<= 1) mx = fmaxf(mx, __shfl_xor(mx, off));
            float scl = mx * (1.0f / 127.0f);
            float isc = (mx > 0.f) ? 127.0f / mx : 0.f;
#pragma unroll
            for (int j = 0; j < 4; j++) {
                int col = n0 + wn * 64 + j * 16 + lm;
                if (ok) C[(size_t)row * 256 + col] = f2b(v[j]);
                int q = (int)rintf(v[j] * isc);
                lds8[rl * 144 + wn * 64 + j * 16 + lm] = (u8)(q & 0xff);
            }
            if (ok && lm == 0) salsc[(size_t)row * 8 + (bn * 2 + wn) * 2 + 1] = scl;
        }
    }
    __syncthreads();
    for (int t = tid; t < 1024; t += 256) {      // 128 rows x 8 x 16B
        int rl = t >> 3;
        int off = (t & 7) * 16;
        int row = m0 + rl;
        if (row < M)
            *(uint4*)(C8 + (size_t)row * 256 + n0 + off) = *(const uint4*)(lds8 + rl * 144 + off);
    }
}

// ---- attention logits -> salsc (als) + ald ----
__global__ __launch_bounds__(256) void k_al(const u16* __restrict__ h, const u16* __restrict__ a_s,
                                            const u16* __restrict__ a_d,
                                            float* __restrict__ salsc, float* __restrict__ ald, int N) {
    int node = blockIdx.x * 4 + (threadIdx.x >> 6);
    if (node >= N) return;
    int lane = threadIdx.x & 63;
    int c0 = lane * 4;
    int head = lane >> 4;
    int ci = c0 & 63;
    ushort4 hv = *(const ushort4*)(h + (size_t)node * 256 + c0);
    float h0 = b2f(hv.x), h1 = b2f(hv.y), h2 = b2f(hv.z), h3 = b2f(hv.w);
    ushort4 sv = *(const ushort4*)(a_s + head * 64 + ci);
    ushort4 dv = *(const ushort4*)(a_d + head * 64 + ci);
    float ps = h0 * b2f(sv.x) + h1 * b2f(sv.y) + h2 * b2f(sv.z) + h3 * b2f(sv.w);
    float pd = h0 * b2f(dv.x) + h1 * b2f(dv.y) + h2 * b2f(dv.z) + h3 * b2f(dv.w);
#pragma unroll
    for (int off = 1; off < 16; off <<= 1) { ps += __shfl_xor(ps, off); pd += __shfl_xor(pd, off); }
    if ((lane & 15) == 0) {
        salsc[(size_t)node * 8 + head * 2] = ps;
        ald[node * 4 + head] = pd;
    }
}

// ---- fused aggregation: no-max softmax, scaled-int8 value gather (256 B/row),
// bf16 self row, bias/BN/LN/ReLU epilogue (+pool). One wave per node.
__global__ __launch_bounds__(256) void k_agg5(
    const u16* __restrict__ h, const u8* __restrict__ h8,
    const float* __restrict__ salsc, const float* __restrict__ ald_,
    const int* __restrict__ ptr, const int* __restrict__ csr,
    const u16* __restrict__ bias, const u16* __restrict__ bng, const u16* __restrict__ bnb,
    const u16* __restrict__ bnm, const u16* __restrict__ bnv,
    const u16* __restrict__ lng, const u16* __restrict__ lnb,
    u16* __restrict__ xout, float* __restrict__ pool, const int* __restrict__ batch, int N) {
    int node = blockIdx.x * 4 + (threadIdx.x >> 6);
    if (node >= N) return;
    int lane = threadIdx.x & 63;
    int c0 = lane * 4;
    int head = lane >> 4;
    float ad = ald_[node * 4 + head];
    // self loop (exact bf16 values)
    float es = salsc[(size_t)node * 8 + head * 2] + ad; es = (es > 0.f) ? es : 0.2f * es;
    float psf = __expf(es);
    float s = psf;
    ushort4 hv = *(const ushort4*)(h + (size_t)node * 256 + c0);
    float a0 = psf * b2f(hv.x), a1 = psf * b2f(hv.y), a2 = psf * b2f(hv.z), a3 = psf * b2f(hv.w);
    int beg = ptr[node], end = ptr[node + 1];
    int i = beg;
    for (; i + 4 <= end; i += 4) {
        int s0 = csr[i], s1 = csr[i + 1], s2 = csr[i + 2], s3 = csr[i + 3];
        float2 f0 = *(const float2*)(salsc + (size_t)s0 * 8 + head * 2);
        float2 f1 = *(const float2*)(salsc + (size_t)s1 * 8 + head * 2);
        float2 f2v = *(const float2*)(salsc + (size_t)s2 * 8 + head * 2);
        float2 f3 = *(const float2*)(salsc + (size_t)s3 * 8 + head * 2);
        u32 r0 = *(const u32*)(h8 + (size_t)s0 * 256 + c0);
        u32 r1 = *(const u32*)(h8 + (size_t)s1 * 256 + c0);
        u32 r2v = *(const u32*)(h8 + (size_t)s2 * 256 + c0);
        u32 r3 = *(const u32*)(h8 + (size_t)s3 * 256 + c0);
        float e0 = f0.x + ad; e0 = (e0 > 0.f) ? e0 : 0.2f * e0;
        float e1 = f1.x + ad; e1 = (e1 > 0.f) ? e1 : 0.2f * e1;
        float e2 = f2v.x + ad; e2 = (e2 > 0.f) ? e2 : 0.2f * e2;
        float e3 = f3.x + ad; e3 = (e3 > 0.f) ? e3 : 0.2f * e3;
        float p0 = __expf(e0), p1 = __expf(e1), p2 = __expf(e2), p3 = __expf(e3);
        s += p0 + p1 + p2 + p3;
        float w0 = p0 * f0.y, w1 = p1 * f1.y, w2 = p2 * f2v.y, w3 = p3 * f3.y;
        a0 += w0 * s8x(r0, 0) + w1 * s8x(r1, 0) + w2 * s8x(r2v, 0) + w3 * s8x(r3, 0);
        a1 += w0 * s8x(r0, 1) + w1 * s8x(r1, 1) + w2 * s8x(r2v, 1) + w3 * s8x(r3, 1);
        a2 += w0 * s8x(r0, 2) + w1 * s8x(r1, 2) + w2 * s8x(r2v, 2) + w3 * s8x(r3, 2);
        a3 += w0 * s8x(r0, 3) + w1 * s8x(r1, 3) + w2 * s8x(r2v, 3) + w3 * s8x(r3, 3);
    }
    for (; i < end; ++i) {
        int s0 = csr[i];
        float2 f0 = *(const float2*)(salsc + (size_t)s0 * 8 + head * 2);
        u32 r0 = *(const u32*)(h8 + (size_t)s0 * 256 + c0);
        float e0 = f0.x + ad; e0 = (e0 > 0.f) ? e0 : 0.2f * e0;
        float p0 = __expf(e0);
        s += p0;
        float w0 = p0 * f0.y;
        a0 += w0 * s8x(r0, 0); a1 += w0 * s8x(r0, 1); a2 += w0 * s8x(r0, 2); a3 += w0 * s8x(r0, 3);
    }
    float inv = 1.0f / (s + 1e-16f);
    float v0 = a0 * inv + b2f(bias[c0 + 0]);
    float v1 = a1 * inv + b2f(bias[c0 + 1]);
    float v2 = a2 * inv + b2f(bias[c0 + 2]);
    float v3 = a3 * inv + b2f(bias[c0 + 3]);
    v0 = (v0 - b2f(bnm[c0 + 0])) * (b2f(bng[c0 + 0]) * rsqrtf(b2f(bnv[c0 + 0]) + 1e-5f)) + b2f(bnb[c0 + 0]);
    v1 = (v1 - b2f(bnm[c0 + 1])) * (b2f(bng[c0 + 1]) * rsqrtf(b2f(bnv[c0 + 1]) + 1e-5f)) + b2f(bnb[c0 + 1]);
    v2 = (v2 - b2f(bnm[c0 + 2])) * (b2f(bng[c0 + 2]) * rsqrtf(b2f(bnv[c0 + 2]) + 1e-5f)) + b2f(bnb[c0 + 2]);
    v3 = (v3 - b2f(bnm[c0 + 3])) * (b2f(bng[c0 + 3]) * rsqrtf(b2f(bnv[c0 + 3]) + 1e-5f)) + b2f(bnb[c0 + 3]);
    float sum = v0 + v1 + v2 + v3;
#pragma unroll
    for (int off = 1; off < 64; off <<= 1) sum += __shfl_xor(sum, off);
    float mu = sum * 0.00390625f;
    float d0 = v0 - mu, d1 = v1 - mu, d2 = v2 - mu, d3 = v3 - mu;
    float q = d0 * d0 + d1 * d1 + d2 * d2 + d3 * d3;
#pragma unroll
    for (int off = 1; off < 64; off <<= 1) q += __shfl_xor(q, off);
    float rstd = rsqrtf(q * 0.00390625f + 1e-5f);
    float y0 = fmaxf(d0 * rstd * b2f(lng[c0 + 0]) + b2f(lnb[c0 + 0]), 0.f);
    float y1 = fmaxf(d1 * rstd * b2f(lng[c0 + 1]) + b2f(lnb[c0 + 1]), 0.f);
    float y2 = fmaxf(d2 * rstd * b2f(lng[c0 + 2]) + b2f(lnb[c0 + 2]), 0.f);
    float y3 = fmaxf(d3 * rstd * b2f(lng[c0 + 3]) + b2f(lnb[c0 + 3]), 0.f);
    if (xout) {
        uint2 o;
        o.x = (u32)f2b(y0) | ((u32)f2b(y1) << 16);
        o.y = (u32)f2b(y2) | ((u32)f2b(y3) << 16);
        *(uint2*)(xout + (size_t)node * 256 + c0) = o;
    }
    if (pool) {
        int g = batch[node];
        float* pp = pool + (size_t)g * 256 + c0;
        atomicAdd(pp + 0, y0); atomicAdd(pp + 1, y1); atomicAdd(pp + 2, y2); atomicAdd(pp + 3, y3);
    }
}

// ---- r2[b] = x[root_b] @ W2[256:512,:] ----
__global__ __launch_bounds__(256) void k_r2(const u16* __restrict__ xc, const u16* __restrict__ w2,
                                            const int* __restrict__ root, float* __restrict__ r2, int N) {
    __shared__ float xs[256];
    int b = blockIdx.x, c = threadIdx.x;
    int rt = root[b]; if (rt >= N) rt = N - 1; if (rt < 0) rt = 0;
    xs[c] = b2f(xc[(size_t)rt * 256 + c]);
    __syncthreads();
    float acc = 0.f;
    for (int k = 0; k < 256; k++) acc += xs[k] * b2f(w2[(size_t)(256 + k) * 256 + c]);
    r2[b * 256 + c] = acc;
}

// ---- final ----
__global__ void k_final(const float* __restrict__ pool, const u16* __restrict__ x2,
                        const int* __restrict__ root, void* __restrict__ out,
                        const int* __restrict__ flag) {
    int b = blockIdx.x, c = threadIdx.x;
    int r0 = root[b], r1 = root[b + 1];
    int cnt = r1 - r0;
    float inv = 1.0f / (float)(cnt > 1 ? cnt : 1);
    float v0 = pool[b * 256 + c] * inv;
    float v1 = (cnt > 0) ? b2f(x2[(size_t)r0 * 256 + c]) : 0.0f;
    if (*flag) {
        float* o = (float*)out;
        o[b * 512 + c] = v0;
        o[b * 512 + 256 + c] = v1;
    } else {
        u16* o = (u16*)out;
        o[b * 512 + c] = f2b(v0);
        o[b * 512 + 256 + c] = f2b(v1);
    }
}

extern "C" void kernel_launch(void* const* d_in, const int* in_sizes, int n_in,
                              void* d_out, int out_size, void* d_ws, size_t ws_size,
                              hipStream_t stream) {
    u16* outp = (u16*)d_out;
    int ogrid = (out_size + 255) / 256;

    if (n_in != 23) {
        k_sentinel<<<ogrid, 256, 0, stream>>>(outp, out_size, (u16)0x44FA);
        return;
    }

    const void* x_raw = d_in[0];
    const int* ei = (const int*)d_in[1];
    const int* batch = (const int*)d_in[2];
    const int NX = in_sizes[0];
    const int E = in_sizes[1] / 2;
    const int N = in_sizes[2];
    const int NW1 = in_sizes[3];
    const int NW2 = in_sizes[13];
    const int B = NGRAPH;

    char* p = (char*)d_ws;
    auto carve = [&](size_t bytes) -> void* {
        void* r = (void*)p; p += (bytes + 255) & ~(size_t)255; return r;
    };
    u16* xc    = (u16*)carve((size_t)NX * 2);
    u16* w1c   = (u16*)carve((size_t)NW1 * 2);
    u16* w2c   = (u16*)carve((size_t)NW2 * 2);
    u16* sc    = (u16*)carve((size_t)18 * 256 * 2);
    u16* wt1   = (u16*)carve((size_t)65536 * 2);
    u16* wt2   = (u16*)carve((size_t)65536 * 2);
    u16* hbuf  = (u16*)carve((size_t)N * 256 * 2);
    u8*  h8    = (u8*)carve((size_t)N * 256);
    u16* x2    = (u16*)carve((size_t)N * 256 * 2);
    float* salsc = (float*)carve((size_t)N * 8 * 4);
    float* ald = (float*)carve((size_t)N * 4 * 4);
    int* deg    = (int*)carve((size_t)(N + 1) * 4);
    int* pscan  = (int*)carve((size_t)(N + 1) * 4);
    int* ptr    = (int*)carve((size_t)(N + 1) * 4);
    int* cursor = (int*)carve((size_t)N * 4);
    int* csr    = (int*)carve((size_t)E * 4);
    int* bsums  = (int*)carve(1024);
    int* root   = (int*)carve((size_t)(B + 1) * 4);
    float* r2   = (float*)carve((size_t)B * 256 * 4);
    float* pool = (float*)carve((size_t)B * 256 * 4);
    int* flag   = (int*)carve(256);

    size_t needed = (size_t)(p - (char*)d_ws);
    if (needed > ws_size) {
        k_sentinel<<<ogrid, 256, 0, stream>>>(outp, out_size, (u16)0x447A);
        return;
    }

    int zmax = (N + 1) > (B * 256) ? (N + 1) : (B * 256);
    k_init<<<(zmax + 255) / 256, 256, 0, stream>>>((const u16*)x_raw, batch, deg, pool, flag, root, N, B);

    k_cvt4<<<(NX / 4 + 255) / 256, 256, 0, stream>>>(x_raw, xc, NX / 4, flag);
    k_cvt4<<<(NW1 / 4 + 255) / 256, 256, 0, stream>>>(d_in[3], w1c, NW1 / 4, flag);
    k_cvt4<<<(NW2 / 4 + 255) / 256, 256, 0, stream>>>(d_in[13], w2c, NW2 / 4, flag);
    k_cvt_small<<<18, 256, 0, stream>>>(
        d_in[4], d_in[5], d_in[6], d_in[7], d_in[8], d_in[9], d_in[10], d_in[11], d_in[12],
        d_in[14], d_in[15], d_in[16], d_in[17], d_in[18], d_in[19], d_in[20], d_in[21], d_in[22],
        sc, flag);

    k_tr2<<<512, 256, 0, stream>>>(w1c, wt1, w2c, wt2);

    k_hist<<<(E + 255) / 256, 256, 0, stream>>>(ei, deg, E);
    int nb1 = (N + 1 + 2047) / 2048;
    k_scan1<<<nb1, 256, 0, stream>>>(deg, pscan, bsums, N + 1);
    k_scan2<<<1, 64, 0, stream>>>(bsums, nb1);
    k_scan3<<<(N + 1 + 255) / 256, 256, 0, stream>>>(pscan, bsums, ptr, cursor, N + 1, N);
    k_fill<<<(E + 255) / 256, 256, 0, stream>>>(ei, cursor, csr, E);

    int mt = (N + 127) / 128;
    int ngrid = (N + 3) / 4;
    // layer 1
    k_gemm<<<mt * 2, 256, 0, stream>>>(xc, wt1, hbuf, h8, salsc, N, nullptr, nullptr);
    k_al<<<ngrid, 256, 0, stream>>>(hbuf, sc + 0 * 256, sc + 1 * 256, salsc, ald, N);
    k_agg5<<<ngrid, 256, 0, stream>>>(hbuf, h8, salsc, ald, ptr, csr,
        sc + 2 * 256, sc + 3 * 256, sc + 4 * 256, sc + 5 * 256, sc + 6 * 256, sc + 7 * 256, sc + 8 * 256,
        x2, nullptr, batch, N);
    // layer 2
    k_r2<<<B, 256, 0, stream>>>(xc, w2c, root, r2, N);
    k_gemm<<<mt * 2, 256, 0, stream>>>(x2, wt2, hbuf, h8, salsc, N, r2, batch);
    k_al<<<ngrid, 256, 0, stream>>>(hbuf, sc + 9 * 256, sc + 10 * 256, salsc, ald, N);
    k_agg5<<<ngrid, 256, 0, stream>>>(hbuf, h8, salsc, ald, ptr, csr,
        sc + 11 * 256, sc + 12 * 256, sc + 13 * 256, sc + 14 * 256, sc + 15 * 256, sc + 16 * 256, sc + 17 * 256,
        nullptr, pool, batch, N);

    k_final<<<B, 256, 0, stream>>>(pool, x2, root, d_out, flag);
    (void)ws_size;
}

// Round 9
// 693.980 us; speedup vs baseline: 1.6459x; 1.0461x over previous
//
#include <hip/hip_runtime.h>
#include <stdint.h>

typedef unsigned short u16;
typedef unsigned int u32;
typedef unsigned char u8;
typedef __bf16 bf16x8 __attribute__((ext_vector_type(8)));
typedef float f32x4 __attribute__((ext_vector_type(4)));

#define NGRAPH 128

__device__ __forceinline__ float b2f(u16 u) {
    union { u32 i; float f; } c; c.i = ((u32)u) << 16; return c.f;
}
__device__ __forceinline__ u16 f2b(float f) {
    union { float f; u32 i; } c; c.f = f;
    u32 r = c.i + 0x7fffu + ((c.i >> 16) & 1u);
    return (u16)(r >> 16);
}

// ---- sentinel (error paths only) ----
__global__ void k_sentinel(u16* __restrict__ out, int n, u16 pat) {
    int i = blockIdx.x * 256 + threadIdx.x;
    if (i < n) out[i] = pat;
}

// ---- fused init: zero deg/pool, dtype detect (block 0), root search (block 1) ----
__global__ __launch_bounds__(256) void k_init(const u16* __restrict__ x, const int* __restrict__ batch,
                                              int* __restrict__ deg, float* __restrict__ pool,
                                              int* __restrict__ flag, int* __restrict__ root,
                                              int N, int B) {
    __shared__ int cnt;
    int i = blockIdx.x * 256 + threadIdx.x;
    if (i < N + 1) deg[i] = 0;
    if (i < B * 256) pool[i] = 0.0f;
    if (blockIdx.x == 0) {
        if (threadIdx.x == 0) cnt = 0;
        __syncthreads();
        int weird = 0;
        for (int k = threadIdx.x; k < 4096; k += 256) {
            u16 u = x[2 * k];                  // fp32 inputs: random low-mantissa halves
            int e = (u >> 7) & 0xff;
            if (e != 0 && (e < 100 || e > 140)) weird++;
        }
        atomicAdd(&cnt, weird);
        __syncthreads();
        if (threadIdx.x == 0) *flag = (cnt > 1024) ? 1 : 0;   // 1 = fp32 inputs
    } else if (blockIdx.x == 1) {
        int b = threadIdx.x;
        if (b <= B) {
            int lo = 0, hi = N;
            while (lo < hi) { int mid = (lo + hi) >> 1; if (batch[mid] < b) lo = mid + 1; else hi = mid; }
            root[b] = lo;
        }
    }
}

// ---- vectorized convert (4 elements/thread, no private arrays -> no scratch) ----
__global__ __launch_bounds__(256) void k_cvt4(const void* __restrict__ src, u16* __restrict__ dst,
                                              int n4, const int* __restrict__ flag) {
    int i = blockIdx.x * 256 + threadIdx.x;
    if (i >= n4) return;
    if (*flag) {
        float4 v = ((const float4*)src)[i];
        ushort4 o;
        o.x = f2b(v.x); o.y = f2b(v.y); o.z = f2b(v.z); o.w = f2b(v.w);
        ((ushort4*)dst)[i] = o;
    } else {
        ((ushort4*)dst)[i] = ((const ushort4*)src)[i];
    }
}

// ---- small-vector convert: 18 blocks x 256 ----
__global__ __launch_bounds__(256) void k_cvt_small(
    const void* p0, const void* p1, const void* p2, const void* p3, const void* p4,
    const void* p5, const void* p6, const void* p7, const void* p8, const void* p9,
    const void* p10, const void* p11, const void* p12, const void* p13, const void* p14,
    const void* p15, const void* p16, const void* p17,
    u16* __restrict__ dst, const int* __restrict__ flag) {
    const void* ps[18] = {p0,p1,p2,p3,p4,p5,p6,p7,p8,p9,p10,p11,p12,p13,p14,p15,p16,p17};
    int f = *flag;
    int vec = blockIdx.x;
    int j = threadIdx.x;
    const void* s = ps[vec];
    dst[vec * 256 + j] = f ? f2b(((const float*)s)[j]) : ((const u16*)s)[j];
}

// ---- dual transpose 256x256 ----
__global__ __launch_bounds__(256) void k_tr2(const u16* __restrict__ w1, u16* __restrict__ wt1,
                                             const u16* __restrict__ w2, u16* __restrict__ wt2) {
    int idx = blockIdx.x * 256 + threadIdx.x;
    int halfsel = idx >> 16;
    int j = idx & 65535;
    int n = j >> 8, k = j & 255;
    if (halfsel == 0) wt1[n * 256 + k] = w1[k * 256 + n];
    else              wt2[n * 256 + k] = w2[k * 256 + n];
}

__global__ __launch_bounds__(256) void k_hist(const int* __restrict__ ei, int* __restrict__ deg, int E) {
    int e = blockIdx.x * 256 + threadIdx.x;
    if (e < E) atomicAdd(&deg[ei[E + e]], 1);
}

__global__ __launch_bounds__(256) void k_scan1(const int* __restrict__ in, int* __restrict__ out,
                                               int* __restrict__ bsums, int total) {
    __shared__ int lds[256];
    int tid = threadIdx.x;
    int base = blockIdx.x * 2048 + tid * 8;
    int v[8]; int ts = 0;
#pragma unroll
    for (int r = 0; r < 8; r++) { int i = base + r; int x = (i < total) ? in[i] : 0; v[r] = x; ts += x; }
    lds[tid] = ts;
    __syncthreads();
    for (int off = 1; off < 256; off <<= 1) {
        int t = (tid >= off) ? lds[tid - off] : 0;
        __syncthreads();
        lds[tid] += t;
        __syncthreads();
    }
    int run = lds[tid] - ts;
#pragma unroll
    for (int r = 0; r < 8; r++) { int i = base + r; if (i < total) out[i] = run; run += v[r]; }
    if (tid == 255) bsums[blockIdx.x] = lds[255];
}

__global__ void k_scan2(int* __restrict__ bsums, int nb) {
    if (threadIdx.x == 0 && blockIdx.x == 0) {
        int run = 0;
        for (int i = 0; i < nb; i++) { int t = bsums[i]; bsums[i] = run; run += t; }
    }
}

__global__ __launch_bounds__(256) void k_scan3(const int* __restrict__ pscan, const int* __restrict__ bsums,
                                               int* __restrict__ ptr, int* __restrict__ cursor,
                                               int total, int N) {
    int i = blockIdx.x * 256 + threadIdx.x;
    if (i >= total) return;
    int val = pscan[i] + bsums[i >> 11];
    ptr[i] = val;
    if (i < N) cursor[i] = val;
}

__global__ __launch_bounds__(256) void k_fill(const int* __restrict__ ei, int* __restrict__ cursor,
                                              int* __restrict__ csr, int E) {
    int e = blockIdx.x * 256 + threadIdx.x;
    if (e < E) {
        int src = ei[e];
        int pos = atomicAdd(&cursor[ei[E + e]], 1);
        csr[pos] = src;
    }
}

// ---- MFMA GEMM: C[M,256](bf16) = A[M,256] @ Bt^T, Bt = [256 n-rows][256 k]
// epilogue: optional += r2[batch[row]][col]; writes bf16 C, int8 C8 in HEAD-SLICED layout
// h8[head][row][64] (per-row-per-head scale into salsc[row*8 + head*2 + 1]).
__global__ __launch_bounds__(256) void k_gemm(const u16* __restrict__ A, const u16* __restrict__ Bt,
                                              u16* __restrict__ C, u8* __restrict__ C8,
                                              float* __restrict__ salsc, int M,
                                              const float* __restrict__ r2, const int* __restrict__ batch) {
    __shared__ __align__(16) u16 smem[128 * 64 * 2];
    u16* As = smem;
    u16* Bs = smem + 128 * 64;
    const int tid = threadIdx.x;
    const int lane = tid & 63;
    const int wave = tid >> 6;
    const int bm = blockIdx.x >> 1;
    const int bn = blockIdx.x & 1;
    const int m0 = bm * 128, n0 = bn * 128;
    const int wm = wave >> 1, wn = wave & 1;
    const int lm = lane & 15, lq = lane >> 4;
    f32x4 acc[4][4] = {};

    for (int k0 = 0; k0 < 256; k0 += 64) {
        uint4 ra[4], rb[4];
#pragma unroll
        for (int it = 0; it < 4; ++it) {
            int t = tid + 256 * it;
            int m = t >> 3;
            int kc = (t & 7) ^ (m & 7);
            int gm = m0 + m; if (gm > M - 1) gm = M - 1;
            ra[it] = *(const uint4*)(A + (size_t)gm * 256 + k0 + kc * 8);
            rb[it] = *(const uint4*)(Bt + (size_t)(n0 + m) * 256 + k0 + kc * 8);
        }
        __syncthreads();
#pragma unroll
        for (int it = 0; it < 4; ++it) {
            int t = tid + 256 * it;
            *(uint4*)(As + t * 8) = ra[it];
            *(uint4*)(Bs + t * 8) = rb[it];
        }
        __syncthreads();
#pragma unroll
        for (int ks = 0; ks < 2; ++ks) {
            int kq = ks * 4 + lq;
            bf16x8 af[4], bfr[4];
#pragma unroll
            for (int i = 0; i < 4; i++) {
                int m = wm * 64 + i * 16 + lm;
                af[i] = *(const bf16x8*)(As + (m * 8 + (kq ^ (m & 7))) * 8);
                int n = wn * 64 + i * 16 + lm;
                bfr[i] = *(const bf16x8*)(Bs + (n * 8 + (kq ^ (n & 7))) * 8);
            }
#pragma unroll
            for (int i = 0; i < 4; i++)
#pragma unroll
                for (int j = 0; j < 4; j++)
                    acc[i][j] = __builtin_amdgcn_mfma_f32_16x16x32_bf16(af[i], bfr[j], acc[i][j], 0, 0, 0);
        }
    }

    __syncthreads();                       // done with As/Bs; reuse as int8 tile
    u8* lds8 = (u8*)smem;                  // 128 rows x 144-padded
#pragma unroll
    for (int i = 0; i < 4; i++) {
#pragma unroll
        for (int r = 0; r < 4; r++) {
            int rl = wm * 64 + i * 16 + lq * 4 + r;
            int row = m0 + rl;
            bool ok = (row < M);
            const float* r2row = (r2 && ok) ? (r2 + (size_t)batch[row] * 256) : nullptr;
            float v[4];
#pragma unroll
            for (int j = 0; j < 4; j++) {
                v[j] = acc[i][j][r];
                if (r2row) v[j] += r2row[n0 + wn * 64 + j * 16 + lm];
            }
            float mx = fmaxf(fmaxf(fabsf(v[0]), fabsf(v[1])), fmaxf(fabsf(v[2]), fabsf(v[3])));
#pragma unroll
            for (int off = 1; off < 16; off <<= 1) mx = fmaxf(mx, __shfl_xor(mx, off));
            float scl = mx * (1.0f / 127.0f);
            float isc = (mx > 0.f) ? 127.0f / mx : 0.f;
#pragma unroll
            for (int j = 0; j < 4; j++) {
                int col = n0 + wn * 64 + j * 16 + lm;
                if (ok) C[(size_t)row * 256 + col] = f2b(v[j]);
                int q = (int)rintf(v[j] * isc);
                lds8[rl * 144 + wn * 64 + j * 16 + lm] = (u8)(q & 0xff);
            }
            if (ok && lm == 0) salsc[(size_t)row * 8 + (bn * 2 + wn) * 2 + 1] = scl;
        }
    }
    __syncthreads();
    // copy out head-sliced: h8[head][row][64]
    for (int t = tid; t < 1024; t += 256) {      // 128 rows x 2 heads x 4 x 16B
        int rl = t >> 3;
        int seg = t & 7;
        int hh = seg >> 2;                       // head half within this bn
        int off = (seg & 3) * 16;
        int row = m0 + rl;
        if (row < M)
            *(uint4*)(C8 + ((size_t)(bn * 2 + hh) * M + row) * 64 + off) =
                *(const uint4*)(lds8 + rl * 144 + hh * 64 + off);
    }
}

// ---- attention logits -> salsc (als) + ald ----
__global__ __launch_bounds__(256) void k_al(const u16* __restrict__ h, const u16* __restrict__ a_s,
                                            const u16* __restrict__ a_d,
                                            float* __restrict__ salsc, float* __restrict__ ald, int N) {
    int node = blockIdx.x * 4 + (threadIdx.x >> 6);
    if (node >= N) return;
    int lane = threadIdx.x & 63;
    int c0 = lane * 4;
    int head = lane >> 4;
    int ci = c0 & 63;
    ushort4 hv = *(const ushort4*)(h + (size_t)node * 256 + c0);
    float h0 = b2f(hv.x), h1 = b2f(hv.y), h2 = b2f(hv.z), h3 = b2f(hv.w);
    ushort4 sv = *(const ushort4*)(a_s + head * 64 + ci);
    ushort4 dv = *(const ushort4*)(a_d + head * 64 + ci);
    float ps = h0 * b2f(sv.x) + h1 * b2f(sv.y) + h2 * b2f(sv.z) + h3 * b2f(sv.w);
    float pd = h0 * b2f(dv.x) + h1 * b2f(dv.y) + h2 * b2f(dv.z) + h3 * b2f(dv.w);
#pragma unroll
    for (int off = 1; off < 16; off <<= 1) { ps += __shfl_xor(ps, off); pd += __shfl_xor(pd, off); }
    if ((lane & 15) == 0) {
        salsc[(size_t)node * 8 + head * 2] = ps;
        ald[node * 4 + head] = pd;
    }
}

// ---- edge weights: aw[h][e] = exp(leaky(als[src]+ald[dst])) * scale8[src,h];
// invs[node][h] = 1/sum_p; selfw[node][h] = p_self/sum_p.
// wave per node: lane = el*4 + h (16 edges x 4 heads per chunk).
__global__ __launch_bounds__(256) void k_attw(
    const float* __restrict__ salsc, const float* __restrict__ ald_,
    const int* __restrict__ ptr, const int* __restrict__ csr,
    float* __restrict__ aw, float* __restrict__ invs, float* __restrict__ selfw, int N, int E) {
    int node = blockIdx.x * 4 + (threadIdx.x >> 6);
    if (node >= N) return;
    int lane = threadIdx.x & 63;
    int h = lane & 3;
    int el = lane >> 2;
    int beg = ptr[node], end = ptr[node + 1];
    float ad = ald_[node * 4 + h];
    float s = 0.f;
    for (int i0 = beg; i0 < end; i0 += 16) {
        int e = i0 + el;
        if (e < end) {
            int src = csr[e];
            float2 f = *(const float2*)(salsc + (size_t)src * 8 + h * 2);
            float lg = f.x + ad; lg = (lg > 0.f) ? lg : 0.2f * lg;
            float p = __expf(lg);
            aw[(size_t)h * E + e] = p * f.y;
            s += p;
        }
    }
#pragma unroll
    for (int off = 4; off < 64; off <<= 1) s += __shfl_xor(s, off);
    float es = salsc[(size_t)node * 8 + h * 2] + ad; es = (es > 0.f) ? es : 0.2f * es;
    float pself = __expf(es);
    s += pself;
    if (el == 0) {
        float inv = 1.0f / (s + 1e-16f);
        invs[node * 4 + h] = inv;
        selfw[node * 4 + h] = pself * inv;
    }
}

// ---- head-phased aggregation: per phase, gather ONE 64B line/edge from the
// L2-resident 3.2MB head slice, weight by streamed aw. Then bias/BN/LN/ReLU (+pool).
// One wave per node; lane owns channels {lane, lane+64, lane+128, lane+192}.
__global__ __launch_bounds__(256) void k_agg6(
    const u16* __restrict__ h, const u8* __restrict__ h8,
    const float* __restrict__ aw, const float* __restrict__ invs_, const float* __restrict__ selfw_,
    const int* __restrict__ ptr, const int* __restrict__ csr,
    const u16* __restrict__ bias, const u16* __restrict__ bng, const u16* __restrict__ bnb,
    const u16* __restrict__ bnm, const u16* __restrict__ bnv,
    const u16* __restrict__ lng, const u16* __restrict__ lnb,
    u16* __restrict__ xout, float* __restrict__ pool, const int* __restrict__ batch, int N, int E) {
    int node = blockIdx.x * 4 + (threadIdx.x >> 6);
    if (node >= N) return;
    int lane = threadIdx.x & 63;
    int beg = ptr[node], end = ptr[node + 1];
    float acc[4];
#pragma unroll
    for (int hh = 0; hh < 4; ++hh) {
        const float* awh = aw + (size_t)hh * E;
        const u8* h8h = h8 + (size_t)hh * N * 64;
        float sa = 0.f, sb = 0.f, sc2 = 0.f, sd = 0.f;
        int i = beg;
        for (; i + 4 <= end; i += 4) {
            int s0 = csr[i], s1 = csr[i + 1], s2 = csr[i + 2], s3 = csr[i + 3];
            float w0 = awh[i], w1 = awh[i + 1], w2 = awh[i + 2], w3 = awh[i + 3];
            float q0 = (float)(signed char)h8h[(size_t)s0 * 64 + lane];
            float q1 = (float)(signed char)h8h[(size_t)s1 * 64 + lane];
            float q2 = (float)(signed char)h8h[(size_t)s2 * 64 + lane];
            float q3 = (float)(signed char)h8h[(size_t)s3 * 64 + lane];
            sa += w0 * q0; sb += w1 * q1; sc2 += w2 * q2; sd += w3 * q3;
        }
        for (; i < end; ++i) {
            int s0 = csr[i];
            float w0 = awh[i];
            sa += w0 * (float)(signed char)h8h[(size_t)s0 * 64 + lane];
        }
        acc[hh] = (sa + sb) + (sc2 + sd);
    }
    float v[4];
#pragma unroll
    for (int hh = 0; hh < 4; ++hh) {
        int c = hh * 64 + lane;
        float inv = invs_[node * 4 + hh];
        float sw = selfw_[node * 4 + hh];
        float self = b2f(h[(size_t)node * 256 + c]);
        float t = acc[hh] * inv + sw * self + b2f(bias[c]);
        v[hh] = (t - b2f(bnm[c])) * (b2f(bng[c]) * rsqrtf(b2f(bnv[c]) + 1e-5f)) + b2f(bnb[c]);
    }
    float sum = v[0] + v[1] + v[2] + v[3];
#pragma unroll
    for (int off = 1; off < 64; off <<= 1) sum += __shfl_xor(sum, off);
    float mu = sum * 0.00390625f;
    float q = 0.f;
#pragma unroll
    for (int hh = 0; hh < 4; ++hh) { v[hh] -= mu; q += v[hh] * v[hh]; }
#pragma unroll
    for (int off = 1; off < 64; off <<= 1) q += __shfl_xor(q, off);
    float rstd = rsqrtf(q * 0.00390625f + 1e-5f);
    float y[4];
#pragma unroll
    for (int hh = 0; hh < 4; ++hh) {
        int c = hh * 64 + lane;
        y[hh] = fmaxf(v[hh] * rstd * b2f(lng[c]) + b2f(lnb[c]), 0.f);
    }
    if (xout) {
#pragma unroll
        for (int hh = 0; hh < 4; ++hh)
            xout[(size_t)node * 256 + hh * 64 + lane] = f2b(y[hh]);
    }
    if (pool) {
        int g = batch[node];
        float* pp = pool + (size_t)g * 256;
#pragma unroll
        for (int hh = 0; hh < 4; ++hh) atomicAdd(pp + hh * 64 + lane, y[hh]);
    }
}

// ---- r2[b] = x[root_b] @ W2[256:512,:] ----
__global__ __launch_bounds__(256) void k_r2(const u16* __restrict__ xc, const u16* __restrict__ w2,
                                            const int* __restrict__ root, float* __restrict__ r2, int N) {
    __shared__ float xs[256];
    int b = blockIdx.x, c = threadIdx.x;
    int rt = root[b]; if (rt >= N) rt = N - 1; if (rt < 0) rt = 0;
    xs[c] = b2f(xc[(size_t)rt * 256 + c]);
    __syncthreads();
    float acc = 0.f;
    for (int k = 0; k < 256; k++) acc += xs[k] * b2f(w2[(size_t)(256 + k) * 256 + c]);
    r2[b * 256 + c] = acc;
}

// ---- final ----
__global__ void k_final(const float* __restrict__ pool, const u16* __restrict__ x2,
                        const int* __restrict__ root, void* __restrict__ out,
                        const int* __restrict__ flag) {
    int b = blockIdx.x, c = threadIdx.x;
    int r0 = root[b], r1 = root[b + 1];
    int cnt = r1 - r0;
    float inv = 1.0f / (float)(cnt > 1 ? cnt : 1);
    float v0 = pool[b * 256 + c] * inv;
    float v1 = (cnt > 0) ? b2f(x2[(size_t)r0 * 256 + c]) : 0.0f;
    if (*flag) {
        float* o = (float*)out;
        o[b * 512 + c] = v0;
        o[b * 512 + 256 + c] = v1;
    } else {
        u16* o = (u16*)out;
        o[b * 512 + c] = f2b(v0);
        o[b * 512 + 256 + c] = f2b(v1);
    }
}

extern "C" void kernel_launch(void* const* d_in, const int* in_sizes, int n_in,
                              void* d_out, int out_size, void* d_ws, size_t ws_size,
                              hipStream_t stream) {
    u16* outp = (u16*)d_out;
    int ogrid = (out_size + 255) / 256;

    if (n_in != 23) {
        k_sentinel<<<ogrid, 256, 0, stream>>>(outp, out_size, (u16)0x44FA);
        return;
    }

    const void* x_raw = d_in[0];
    const int* ei = (const int*)d_in[1];
    const int* batch = (const int*)d_in[2];
    const int NX = in_sizes[0];
    const int E = in_sizes[1] / 2;
    const int N = in_sizes[2];
    const int NW1 = in_sizes[3];
    const int NW2 = in_sizes[13];
    const int B = NGRAPH;

    char* p = (char*)d_ws;
    auto carve = [&](size_t bytes) -> void* {
        void* r = (void*)p; p += (bytes + 255) & ~(size_t)255; return r;
    };
    u16* xc    = (u16*)carve((size_t)NX * 2);
    u16* w1c   = (u16*)carve((size_t)NW1 * 2);
    u16* w2c   = (u16*)carve((size_t)NW2 * 2);
    u16* sc    = (u16*)carve((size_t)18 * 256 * 2);
    u16* wt1   = (u16*)carve((size_t)65536 * 2);
    u16* wt2   = (u16*)carve((size_t)65536 * 2);
    u16* hbuf  = (u16*)carve((size_t)N * 256 * 2);
    u8*  h8    = (u8*)carve((size_t)N * 256);
    u16* x2    = (u16*)carve((size_t)N * 256 * 2);
    float* salsc = (float*)carve((size_t)N * 8 * 4);
    float* ald = (float*)carve((size_t)N * 4 * 4);
    float* aw  = (float*)carve((size_t)E * 4 * 4);
    float* invs  = (float*)carve((size_t)N * 4 * 4);
    float* selfw = (float*)carve((size_t)N * 4 * 4);
    int* deg    = (int*)carve((size_t)(N + 1) * 4);
    int* pscan  = (int*)carve((size_t)(N + 1) * 4);
    int* ptr    = (int*)carve((size_t)(N + 1) * 4);
    int* cursor = (int*)carve((size_t)N * 4);
    int* csr    = (int*)carve((size_t)E * 4);
    int* bsums  = (int*)carve(1024);
    int* root   = (int*)carve((size_t)(B + 1) * 4);
    float* r2   = (float*)carve((size_t)B * 256 * 4);
    float* pool = (float*)carve((size_t)B * 256 * 4);
    int* flag   = (int*)carve(256);

    size_t needed = (size_t)(p - (char*)d_ws);
    if (needed > ws_size) {
        k_sentinel<<<ogrid, 256, 0, stream>>>(outp, out_size, (u16)0x447A);
        return;
    }

    int zmax = (N + 1) > (B * 256) ? (N + 1) : (B * 256);
    k_init<<<(zmax + 255) / 256, 256, 0, stream>>>((const u16*)x_raw, batch, deg, pool, flag, root, N, B);

    k_cvt4<<<(NX / 4 + 255) / 256, 256, 0, stream>>>(x_raw, xc, NX / 4, flag);
    k_cvt4<<<(NW1 / 4 + 255) / 256, 256, 0, stream>>>(d_in[3], w1c, NW1 / 4, flag);
    k_cvt4<<<(NW2 / 4 + 255) / 256, 256, 0, stream>>>(d_in[13], w2c, NW2 / 4, flag);
    k_cvt_small<<<18, 256, 0, stream>>>(
        d_in[4], d_in[5], d_in[6], d_in[7], d_in[8], d_in[9], d_in[10], d_in[11], d_in[12],
        d_in[14], d_in[15], d_in[16], d_in[17], d_in[18], d_in[19], d_in[20], d_in[21], d_in[22],
        sc, flag);

    k_tr2<<<512, 256, 0, stream>>>(w1c, wt1, w2c, wt2);

    k_hist<<<(E + 255) / 256, 256, 0, stream>>>(ei, deg, E);
    int nb1 = (N + 1 + 2047) / 2048;
    k_scan1<<<nb1, 256, 0, stream>>>(deg, pscan, bsums, N + 1);
    k_scan2<<<1, 64, 0, stream>>>(bsums, nb1);
    k_scan3<<<(N + 1 + 255) / 256, 256, 0, stream>>>(pscan, bsums, ptr, cursor, N + 1, N);
    k_fill<<<(E + 255) / 256, 256, 0, stream>>>(ei, cursor, csr, E);

    int mt = (N + 127) / 128;
    int ngrid = (N + 3) / 4;
    // layer 1
    k_gemm<<<mt * 2, 256, 0, stream>>>(xc, wt1, hbuf, h8, salsc, N, nullptr, nullptr);
    k_al<<<ngrid, 256, 0, stream>>>(hbuf, sc + 0 * 256, sc + 1 * 256, salsc, ald, N);
    k_attw<<<ngrid, 256, 0, stream>>>(salsc, ald, ptr, csr, aw, invs, selfw, N, E);
    k_agg6<<<ngrid, 256, 0, stream>>>(hbuf, h8, aw, invs, selfw, ptr, csr,
        sc + 2 * 256, sc + 3 * 256, sc + 4 * 256, sc + 5 * 256, sc + 6 * 256, sc + 7 * 256, sc + 8 * 256,
        x2, nullptr, batch, N, E);
    // layer 2
    k_r2<<<B, 256, 0, stream>>>(xc, w2c, root, r2, N);
    k_gemm<<<mt * 2, 256, 0, stream>>>(x2, wt2, hbuf, h8, salsc, N, r2, batch);
    k_al<<<ngrid, 256, 0, stream>>>(hbuf, sc + 9 * 256, sc + 10 * 256, salsc, ald, N);
    k_attw<<<ngrid, 256, 0, stream>>>(salsc, ald, ptr, csr, aw, invs, selfw, N, E);
    k_agg6<<<ngrid, 256, 0, stream>>>(hbuf, h8, aw, invs, selfw, ptr, csr,
        sc + 11 * 256, sc + 12 * 256, sc + 13 * 256, sc + 14 * 256, sc + 15 * 256, sc + 16 * 256, sc + 17 * 256,
        nullptr, pool, batch, N, E);

    k_final<<<B, 256, 0, stream>>>(pool, x2, root, d_out, flag);
    (void)ws_size;
}